// Round 8
// baseline (306.997 us; speedup 1.0000x reference)
//
#include <hip/hip_runtime.h>
#include <stdint.h>

#define Bn 4
#define An 3
#define Hn 168
#define Wn 256
#define Mn 32
#define HWn (Hn*Wn)
#define Nn (HWn*An)          // 129024
#define POS_CAP 8192
#define NPERIM 256
#define NPOSMAX 128
#define FG_THR 0.7f
#define BG_THR 0.3f
#define BETA (1.0f/9.0f)

#define NBLK 504             // blocks per image (APT=1, R6/R7: occupancy hides atomics)
#define NWAVES (NBLK*4)      // 2016 waves per image
#define TSEG_CAP 64          // per-wave deferred segment
#define NSEG_CAP 64          // per-wave certain-negative fallback segment
#define XSEG_CAP 256         // per-k2-block late-negative fallback segment
#define BIN_HOT 960          // bins >= BIN_HOT are bucketed (top-64: ~2900 entries >> 256)
#define NHOT 64
#define HB_CAP 256           // per-hot-bin bucket capacity (expect ~46)

// ---- workspace layout (uint32 word offsets) ----
#define OFF_POSCNT 0            // Bn
#define OFF_DONEI  4            // Bn (per-image k2 ticket)
#define OFF_COUNT  8            // 1
#define OFF_CLS    9            // 1 (float bits)
#define OFF_REG    10           // 1 (float bits)
#define OFF_DONEA  11           // 1 (cross-image ticket)
#define OFF_BINCNT 16           // Bn*1024 -> 4112
#define OFF_BINBCE 4112         // Bn*1024 -> 8208
#define ZERO_WORDS 8208
#define OFF_PCM    8208         // Bn*NBLK*32 = 64512  -> 72720
#define OFF_WPCM   72720        // Bn*NWAVES*32 = 258048 -> 330768
#define OFF_TSEGC  330768       // Bn*NWAVES = 8064    -> 338832
#define OFF_NSEGC  338832       // Bn*NWAVES = 8064    -> 346896
#define OFF_XSEGC  346896       // Bn*NBLK = 2016      -> 348912
#define OFF_PLIST  348912       // Bn*POS_CAP*2 = 65536 -> 414448
#define OFF_HBUCK  414448       // Bn*NHOT*HB_CAP*2 = 131072 -> 545520
#define OFF_TSEG   545520       // Bn*NWAVES*TSEG_CAP*4 = 2064384 -> 2609904
#define OFF_NSEG   2609904      // Bn*NWAVES*NSEG_CAP*2 = 1032192 -> 3642096
#define OFF_XSEG   3642096      // Bn*NBLK*XSEG_CAP*2 = 1032192 -> 4674288 (~18.7MB)

// ------------------- threefry2x32 (20 rounds) -------------------
__device__ __forceinline__ uint32_t rotl32(uint32_t v, int n) { return (v << n) | (v >> (32 - n)); }

__device__ __forceinline__ void tf2x32(uint32_t k0, uint32_t k1, uint32_t x0, uint32_t x1,
                                       uint32_t& o0, uint32_t& o1) {
    uint32_t k2 = k0 ^ k1 ^ 0x1BD11BDAu;
    x0 += k0; x1 += k1;
    x0 += x1; x1 = rotl32(x1, 13); x1 ^= x0;
    x0 += x1; x1 = rotl32(x1, 15); x1 ^= x0;
    x0 += x1; x1 = rotl32(x1, 26); x1 ^= x0;
    x0 += x1; x1 = rotl32(x1, 6);  x1 ^= x0;
    x0 += k1; x1 += k2 + 1u;
    x0 += x1; x1 = rotl32(x1, 17); x1 ^= x0;
    x0 += x1; x1 = rotl32(x1, 29); x1 ^= x0;
    x0 += x1; x1 = rotl32(x1, 16); x1 ^= x0;
    x0 += x1; x1 = rotl32(x1, 24); x1 ^= x0;
    x0 += k2; x1 += k0 + 2u;
    x0 += x1; x1 = rotl32(x1, 13); x1 ^= x0;
    x0 += x1; x1 = rotl32(x1, 15); x1 ^= x0;
    x0 += x1; x1 = rotl32(x1, 26); x1 ^= x0;
    x0 += x1; x1 = rotl32(x1, 6);  x1 ^= x0;
    x0 += k0; x1 += k1 + 3u;
    x0 += x1; x1 = rotl32(x1, 17); x1 ^= x0;
    x0 += x1; x1 = rotl32(x1, 29); x1 ^= x0;
    x0 += x1; x1 = rotl32(x1, 16); x1 ^= x0;
    x0 += x1; x1 = rotl32(x1, 24); x1 ^= x0;
    x0 += k1; x1 += k2 + 4u;
    x0 += x1; x1 = rotl32(x1, 13); x1 ^= x0;
    x0 += x1; x1 = rotl32(x1, 15); x1 ^= x0;
    x0 += x1; x1 = rotl32(x1, 26); x1 ^= x0;
    x0 += x1; x1 = rotl32(x1, 6);  x1 ^= x0;
    x0 += k2; x1 += k0 + 5u;
    o0 = x0; o1 = x1;
}

__device__ __forceinline__ uint32_t rng_m23(uint32_t k0, uint32_t k1, uint32_t i) {
    uint32_t o0, o1;
    tf2x32(k0, k1, 0u, i, o0, o1);
    return (o0 ^ o1) >> 9;
}

__device__ __forceinline__ uint32_t vload(const uint32_t* p) {
    return *(const volatile uint32_t*)p;
}

// device-scope visible 8B store (for same-kernel cross-block consumption)
__device__ __forceinline__ void st64(uint2* p, uint2 v) {
    atomicExch((unsigned long long*)p,
               ((unsigned long long)v.y << 32) | (unsigned long long)v.x);
}

// ------------------- IoU (single definition) ------------
__device__ __forceinline__ float iou_one(float a0, float a1, float a2, float a3,
                                         float t0, float t1, float t2, float t3) {
    float xtl = fmaxf(a0, t0), ytl = fmaxf(a1, t1);
    float xrb = fminf(a2, t2), yrb = fminf(a3, t3);
    float iw = fmaxf(xrb - xtl + 1.0f, 0.0f);
    float ih = fmaxf(yrb - ytl + 1.0f, 0.0f);
    float inter = iw * ih;
    float area1 = (a2 - a0 + 1.0f) * (a3 - a1 + 1.0f);
    float area2 = (t2 - t0 + 1.0f) * (t3 - t1 + 1.0f);
    return inter * __builtin_amdgcn_rcpf(area1 + area2 - inter);
}

__device__ __forceinline__ float bce0(float l) {   // BCE(l, target=0)
    return fmaxf(l, 0.0f) + log1pf(expf(-fabsf(l)));
}

// ------------------- selection order (JAX top_k) -------------------
__device__ __forceinline__ bool sel_less(uint2 a, uint2 b) {
    return (a.x > b.x) || (a.x == b.x && a.y < b.y);
}

__device__ void bitonic_sort_shared(uint2* buf, int n) {   // n = pow2
    for (int k = 2; k <= n; k <<= 1) {
        for (int j = k >> 1; j > 0; j >>= 1) {
            for (int t = (int)threadIdx.x; t < n; t += (int)blockDim.x) {
                int ixj = t ^ j;
                if (ixj > t) {
                    uint2 x = buf[t], y = buf[ixj];
                    bool up = ((t & k) == 0);
                    bool sw = up ? sel_less(y, x) : sel_less(x, y);
                    if (sw) { buf[t] = y; buf[ixj] = x; }
                }
            }
            __syncthreads();
        }
    }
}

// =====================================================================================
// K0: zero control + bin counters/sums.
// =====================================================================================
__global__ void __launch_bounds__(256) k0_init(uint32_t* __restrict__ ws) {
    int i = blockIdx.x * 256 + (int)threadIdx.x;
    if (i < ZERO_WORDS) ws[i] = 0u;
}

// =====================================================================================
// K1: IoU + categorize. One anchor/thread.
//  pos -> PLIST ticket (rare). defer -> per-wave TSEG (no atomics).
//  neg -> fire-and-forget BINCNT/BINBCE; HOT bins (>=960) additionally get a returning
//  slot + bucket write (~6% of negs: kills 12MB of partial-line scatter, R7 WRITE_SIZE);
//  per-wave NSEG fallback segment (ballot-compacted, coalesced, no atomics).
// =====================================================================================
__global__ void __launch_bounds__(256) k1_iou(const float* __restrict__ anchors,
                                              const float* __restrict__ targets,
                                              const float* __restrict__ sizes,
                                              const float* __restrict__ logits,
                                              uint32_t* __restrict__ ws) {
    const int b = blockIdx.y, j = blockIdx.x, tid = threadIdx.x;
    const int wid = tid >> 6, lane = tid & 63;
    __shared__ float part[4][Mn];

    uint32_t key0, key1;
    tf2x32(0u, 42u, 0u, (uint32_t)b, key0, key1);

    const int i = j * 256 + tid;
    float4 av = ((const float4*)anchors)[b * Nn + i];

    float rowmax = -1.0f; int ori = 0; uint32_t tie = 0u;
    float mycm = 0.0f;
    #pragma unroll 4
    for (int t = 0; t < Mn; ++t) {
        float4 tv = ((const float4*)targets)[b * Mn + t];
        float io = iou_one(av.x, av.y, av.z, av.w, tv.x, tv.y, tv.z, tv.w);
        if (io > rowmax) { rowmax = io; ori = t; }
        float m0 = io;
        #pragma unroll
        for (int o = 32; o > 0; o >>= 1) m0 = fmaxf(m0, __shfl_xor(m0, o, 64));
        if (lane == t) mycm = m0;
        tie |= (io == m0) ? (1u << t) : 0u;
    }

    const int wimg = j * 4 + wid;
    if (lane < Mn) {
        ws[OFF_WPCM + ((size_t)b * NWAVES + wimg) * 32 + lane] = __float_as_uint(mycm);
        part[wid][lane] = mycm;
    }
    __syncthreads();
    if (tid < Mn) {
        float v = fmaxf(fmaxf(part[0][tid], part[1][tid]),
                        fmaxf(part[2][tid], part[3][tid]));
        ws[OFF_PCM + ((size_t)b * NBLK + j) * Mn + tid] = __float_as_uint(v);
    }

    const float sh = sizes[b * 2 + 0], sw = sizes[b * 2 + 1];
    unsigned long long lt_mask = (lane == 63) ? 0x7FFFFFFFFFFFFFFFull
                                              : ((1ull << lane) - 1ull);
    bool inside = (av.x >= 0.0f) && (av.y >= 0.0f) &&
                  (av.z <= sw - 1.0f) && (av.w <= sh - 1.0f);
    bool fg = rowmax >= FG_THR;
    bool bg = rowmax < BG_THR;
    bool posn   = inside && fg;
    bool defern = inside && !fg && (tie != 0u);
    bool negn   = inside && bg && (tie == 0u);
    uint32_t m = rng_m23(key0, key1, (uint32_t)i);

    const int a_ = i % An, hw_ = i / An;
    float lneg = 0.0f;
    if (negn) lneg = logits[(b * An + a_) * HWn + hw_];

    unsigned long long pmask = __ballot(posn);
    if (pmask) {
        int leader = __ffsll((long long)pmask) - 1;
        uint32_t bb = 0;
        if (lane == leader) bb = atomicAdd(&ws[OFF_POSCNT + b], (uint32_t)__popcll(pmask));
        bb = __shfl(bb, leader, 64);
        if (posn) {
            uint32_t p = bb + (uint32_t)__popcll(pmask & lt_mask);
            if (p < POS_CAP)
                ((uint2*)(ws + OFF_PLIST))[(size_t)b * POS_CAP + p] =
                    make_uint2(m, (uint32_t)i | ((uint32_t)ori << 17));
        }
    }
    unsigned long long dmask = __ballot(defern);
    if (defern) {
        uint32_t slot = (uint32_t)__popcll(dmask & lt_mask);
        ((uint4*)(ws + OFF_TSEG))[((size_t)b * NWAVES + wimg) * TSEG_CAP + slot] =
            make_uint4(tie, m,
                       (uint32_t)i | ((uint32_t)ori << 17) | (bg ? (1u << 22) : 0u), 0u);
    }
    unsigned long long nmask = __ballot(negn);
    if (negn) {
        // fallback segment: ballot-compacted, coalesced, no atomics
        uint32_t slot = (uint32_t)__popcll(nmask & lt_mask);
        ((uint2*)(ws + OFF_NSEG))[((size_t)b * NWAVES + wimg) * NSEG_CAP + slot] =
            make_uint2(m, (uint32_t)i);
        int bin = (int)(m >> 13);
        if (bin >= BIN_HOT) {
            uint32_t s2 = atomicAdd(&ws[OFF_BINCNT + (b << 10) + bin], 1u);   // returning
            if (s2 < HB_CAP)
                ((uint2*)(ws + OFF_HBUCK))[((size_t)b * NHOT + (bin - BIN_HOT)) * HB_CAP + s2] =
                    make_uint2(m, (uint32_t)i);
        } else {
            atomicAdd(&ws[OFF_BINCNT + (b << 10) + bin], 1u);                 // fire-and-forget
        }
        atomicAdd((float*)&ws[OFF_BINBCE + (b << 10) + bin], bce0(lneg));     // fire-and-forget
    }
    if (lane == 0) {
        ws[OFF_TSEGC + b * NWAVES + wimg] = (uint32_t)__popcll(dmask);
        ws[OFF_NSEGC + b * NWAVES + wimg] = (uint32_t)__popcll(nmask);
    }
}

// =====================================================================================
// K2: full grid (504 x 4). Per block: coalesced CM reduce (R6 fix: stride-256 columns)
// -> eqmask for own 4 waves -> resolve own deferred ties. Then per-image ticket; the
// last block of each image runs the finalize (scan + sorts + losses + output).
// Same-kernel cross-block data uses device-scope atomic stores (st64).
// =====================================================================================
__global__ void __launch_bounds__(256) k2_resolve(const float* __restrict__ anchors,
                                                  const float* __restrict__ targets,
                                                  const float* __restrict__ logits,
                                                  const float* __restrict__ bregs,
                                                  uint32_t* __restrict__ ws,
                                                  float* __restrict__ out) {
    const int b = blockIdx.y, j = blockIdx.x, tid = threadIdx.x;
    const int lane = tid & 63;
    __shared__ uint32_t cmb[Mn];
    __shared__ uint32_t eqs[4];
    __shared__ uint32_t cnts[4];
    __shared__ uint32_t sx_cnt, s_fcnt;
    __shared__ int s_last, s_bd, s_need;
    union U {
        float part[8][32];
        struct { uint32_t csum[256]; uint2 buf[2048]; float red[256]; } fin;
    };
    __shared__ U u;

    if (tid < 4) { eqs[tid] = 0u; cnts[tid] = ws[OFF_TSEGC + b * NWAVES + j * 4 + tid]; }
    if (tid == 0) sx_cnt = 0u;
    __syncthreads();
    const int total = (int)(cnts[0] + cnts[1] + cnts[2] + cnts[3]);

    if (total > 0) {
        // ---- coalesced CM reduce: thread strides by 256 over PCM (column tid%32 fixed) ----
        {
            float acc = 0.0f;
            const uint32_t* pcm = ws + OFF_PCM + (size_t)b * NBLK * Mn;
            for (int w = tid; w < NBLK * Mn; w += 256)
                acc = fmaxf(acc, __uint_as_float(pcm[w]));
            u.part[tid >> 5][tid & 31] = acc;
            __syncthreads();
            if (tid < Mn) {
                float v = u.part[0][tid];
                #pragma unroll
                for (int q = 1; q < 8; ++q) v = fmaxf(v, u.part[q][tid]);
                cmb[tid] = __float_as_uint(v);
            }
            __syncthreads();
        }
        // eqmask for this block's 4 k1-waves
        if (tid < 128) {
            int lw = tid >> 5, t2 = tid & 31;
            uint32_t wv = ws[OFF_WPCM + ((size_t)b * NWAVES + j * 4 + lw) * 32 + t2];
            if (wv == cmb[t2]) atomicOr(&eqs[lw], 1u << t2);
        }
        __syncthreads();

        const uint32_t c0 = cnts[0], c1 = cnts[1], c2 = cnts[2], c3 = cnts[3];
        unsigned long long lt_mask = (lane == 63) ? 0x7FFFFFFFFFFFFFFFull
                                                  : ((1ull << lane) - 1ull);
        for (int f = tid; f < total; f += 256) {
            int lw, o;
            if ((uint32_t)f < c0)                { lw = 0; o = f; }
            else if ((uint32_t)f < c0 + c1)      { lw = 1; o = f - (int)c0; }
            else if ((uint32_t)f < c0 + c1 + c2) { lw = 2; o = f - (int)(c0 + c1); }
            else                                 { lw = 3; o = f - (int)(c0 + c1 + c2); }
            uint4 e = ((const uint4*)(ws + OFF_TSEG))
                          [((size_t)b * NWAVES + j * 4 + lw) * TSEG_CAP + o];
            int i = (int)(e.z & 0x1FFFFu);
            bool restored = (e.x & eqs[lw]) != 0u;

            unsigned long long rmask = __ballot(restored);
            if (rmask) {
                int leader = __ffsll((long long)rmask) - 1;
                uint32_t bb = 0;
                if (lane == leader) bb = atomicAdd(&ws[OFF_POSCNT + b], (uint32_t)__popcll(rmask));
                bb = __shfl(bb, leader, 64);
                if (restored) {
                    uint32_t p = bb + (uint32_t)__popcll(rmask & lt_mask);
                    if (p < POS_CAP)
                        st64(&((uint2*)(ws + OFF_PLIST))[(size_t)b * POS_CAP + p],
                             make_uint2(e.y, e.z & 0x3FFFFFu));
                }
            }
            if (!restored && (e.z & (1u << 22))) {   // late negative
                uint32_t m = e.y;
                int bin = (int)(m >> 13);
                if (bin >= BIN_HOT) {
                    uint32_t s2 = atomicAdd(&ws[OFF_BINCNT + (b << 10) + bin], 1u);
                    if (s2 < HB_CAP)
                        st64(&((uint2*)(ws + OFF_HBUCK))
                                 [((size_t)b * NHOT + (bin - BIN_HOT)) * HB_CAP + s2],
                             make_uint2(m, (uint32_t)i));
                } else {
                    atomicAdd(&ws[OFF_BINCNT + (b << 10) + bin], 1u);
                }
                int a = i % An, hw = i / An;
                float l = logits[(b * An + a) * HWn + hw];
                atomicAdd((float*)&ws[OFF_BINBCE + (b << 10) + bin], bce0(l));
                uint32_t xs = atomicAdd(&sx_cnt, 1u);    // LDS
                if (xs < XSEG_CAP)
                    st64(&((uint2*)(ws + OFF_XSEG))[((size_t)b * NBLK + j) * XSEG_CAP + xs],
                         make_uint2(m, (uint32_t)i));
            }
        }
    }
    __syncthreads();
    if (tid == 0) ws[OFF_XSEGC + b * NBLK + j] = sx_cnt;

    // ---- per-image ticket: last block runs the finalize ----
    __threadfence();
    __syncthreads();
    if (tid == 0) {
        uint32_t old = atomicAdd(&ws[OFF_DONEI + b], 1u);
        s_last = (old == (uint32_t)(NBLK - 1)) ? 1 : 0;
    }
    __syncthreads();
    if (!s_last) return;

    // ================= finalize for image b (256 threads) =================
    __threadfence();   // acquire
    float cls = 0.0f, reg = 0.0f;

    // suffix scan of 1024 bin counts, 4 bins/thread (R2 k25 pattern)
    uint32_t c4[4];
    #pragma unroll
    for (int q = 0; q < 4; ++q) c4[q] = vload(ws + OFF_BINCNT + (b << 10) + 4 * tid + q);
    u.fin.csum[tid] = c4[0] + c4[1] + c4[2] + c4[3];
    __syncthreads();
    for (int off = 1; off < 256; off <<= 1) {
        uint32_t mine = u.fin.csum[tid];
        uint32_t add = (tid + off < 256) ? u.fin.csum[tid + off] : 0u;
        __syncthreads();
        u.fin.csum[tid] = mine + add;
        __syncthreads();
    }
    uint32_t pc = vload(ws + OFF_POSCNT + b);
    int num_pos = (pc < (uint32_t)NPOSMAX) ? (int)pc : NPOSMAX;
    int k_neg = NPERIM - num_pos;
    uint32_t total_n = u.fin.csum[0];
    if (tid == 0 && (int)total_n < k_neg) { s_bd = -1; s_need = 0; }
    {
        uint32_t incl = u.fin.csum[tid];
        uint32_t nxt = (tid < 255) ? u.fin.csum[tid + 1] : 0u;
        if ((int)total_n >= k_neg && (int)incl >= k_neg && (int)nxt < k_neg) {
            int cum = (int)nxt, boundary = -1, needed = 0;
            #pragma unroll
            for (int q = 3; q >= 0; --q) {
                int c = (int)c4[q];
                if (cum + c >= k_neg) { boundary = 4 * tid + q; needed = k_neg - cum; break; }
                cum += c;
            }
            s_bd = boundary; s_need = needed;
        }
    }
    if (tid == 0) {
        int sel_negs = ((int)total_n < k_neg) ? (int)total_n : k_neg;
        atomicAdd(&ws[OFF_COUNT], (uint32_t)(num_pos + sel_negs));
    }
    __syncthreads();
    const int bd = s_bd, need = s_need;
    #pragma unroll
    for (int q = 0; q < 4; ++q) {
        int bin = 4 * tid + q;
        if (bin > bd) cls += __uint_as_float(vload(ws + OFF_BINBCE + (b << 10) + bin));
    }
    __syncthreads();   // csum dead; buf phase begins

    if (need > 0) {
        int cnt;
        if (bd >= BIN_HOT) {
            cnt = (int)vload(ws + OFF_BINCNT + (b << 10) + bd);
            if (cnt > HB_CAP) cnt = HB_CAP;
            const uint2* bkt = (const uint2*)(ws + OFF_HBUCK) +
                               ((size_t)b * NHOT + (bd - BIN_HOT)) * HB_CAP;
            for (int t = tid; t < cnt; t += 256) u.fin.buf[t] = bkt[t];
        } else {
            // fallback (probability ~0 on this data; correctness-only): gather bin==bd
            if (tid == 0) s_fcnt = 0u;
            __syncthreads();
            for (int w = 0; w < NWAVES; ++w) {
                int cw = (int)vload(ws + OFF_NSEGC + b * NWAVES + w);
                const uint2* ns = (const uint2*)(ws + OFF_NSEG) +
                                  ((size_t)b * NWAVES + w) * NSEG_CAP;
                for (int idx = tid; idx < cw; idx += 256) {
                    uint2 e = ns[idx];
                    if ((int)(e.x >> 13) == bd) {
                        uint32_t q2 = atomicAdd(&s_fcnt, 1u);
                        if (q2 < 2048u) u.fin.buf[q2] = e;
                    }
                }
            }
            for (int j2 = 0; j2 < NBLK; ++j2) {
                int cx = (int)vload(ws + OFF_XSEGC + b * NBLK + j2);
                if (cx > XSEG_CAP) cx = XSEG_CAP;
                const uint2* xs = (const uint2*)(ws + OFF_XSEG) +
                                  ((size_t)b * NBLK + j2) * XSEG_CAP;
                for (int idx = tid; idx < cx; idx += 256) {
                    uint2 e = xs[idx];
                    if ((int)(e.x >> 13) == bd) {
                        uint32_t q2 = atomicAdd(&s_fcnt, 1u);
                        if (q2 < 2048u) u.fin.buf[q2] = e;
                    }
                }
            }
            __syncthreads();
            cnt = (int)s_fcnt; if (cnt > 2048) cnt = 2048;
        }
        int npad = 1; while (npad < cnt) npad <<= 1;
        for (int t = tid; t < npad; t += 256) if (t >= cnt) u.fin.buf[t] = make_uint2(0u, 0xFFFFFFFFu);
        __syncthreads();
        bitonic_sort_shared(u.fin.buf, npad);
        int sel = (need < cnt) ? need : cnt;
        for (int t = tid; t < sel; t += 256) {
            int i = (int)u.fin.buf[t].y;
            int a = i % An, hw = i / An;
            float l = logits[(b * An + a) * HWn + hw];
            cls += bce0(l);
        }
    }
    __syncthreads();

    // positives
    {
        int pci = (pc < (uint32_t)POS_CAP) ? (int)pc : POS_CAP;
        const uint2* plist = (const uint2*)(ws + OFF_PLIST) + (size_t)b * POS_CAP;
        int psel = (pci < NPOSMAX) ? pci : NPOSMAX;
        bool use_buf = false;
        if (pci > NPOSMAX) {
            int n = (pci < 2048) ? pci : 2048;
            for (int t = tid; t < n; t += 256) u.fin.buf[t] = plist[t];
            int npad = 1; while (npad < n) npad <<= 1;
            for (int t = tid; t < npad; t += 256) if (t >= n) u.fin.buf[t] = make_uint2(0u, 0xFFFFFFFFu);
            __syncthreads();
            bitonic_sort_shared(u.fin.buf, npad);
            use_buf = true;
            psel = (NPOSMAX < n) ? NPOSMAX : n;
        }
        for (int t = tid; t < psel; t += 256) {
            uint32_t packed = use_buf ? u.fin.buf[t].y : plist[t].y;
            int i = (int)(packed & 0x1FFFFu);
            int orit = (int)((packed >> 17) & 0x1Fu);
            int a = i % An, hw = i / An;
            float l = logits[(b * An + a) * HWn + hw];
            cls += fmaxf(l, 0.0f) - l + log1pf(expf(-fabsf(l)));   // BCE(l,1)
            float4 avx = ((const float4*)anchors)[b * Nn + i];
            float4 tv = ((const float4*)targets)[b * Mn + orit];
            float aws = avx.z - avx.x + 1.0f, ahs = avx.w - avx.y + 1.0f;
            float axc = avx.x + 0.5f * aws, ayc = avx.y + 0.5f * ahs;
            float tws = tv.z - tv.x + 1.0f, ths = tv.w - tv.y + 1.0f;
            float txc = tv.x + 0.5f * tws, tyc = tv.y + 0.5f * ths;
            float off0 = (txc - axc) / aws;
            float off1 = (tyc - ayc) / ahs;
            float off2 = logf(tws / aws);
            float off3 = logf(ths / ahs);
            float br0 = bregs[(b * 12 + a * 4 + 0) * HWn + hw];
            float br1 = bregs[(b * 12 + a * 4 + 1) * HWn + hw];
            float br2 = bregs[(b * 12 + a * 4 + 2) * HWn + hw];
            float br3 = bregs[(b * 12 + a * 4 + 3) * HWn + hw];
            float d;
            d = fabsf(br0 - off0); reg += (d < BETA) ? 0.5f * d * d / BETA : d - 0.5f * BETA;
            d = fabsf(br1 - off1); reg += (d < BETA) ? 0.5f * d * d / BETA : d - 0.5f * BETA;
            d = fabsf(br2 - off2); reg += (d < BETA) ? 0.5f * d * d / BETA : d - 0.5f * BETA;
            d = fabsf(br3 - off3); reg += (d < BETA) ? 0.5f * d * d / BETA : d - 0.5f * BETA;
        }
    }
    __syncthreads();

    // reductions + cross-image epilogue
    u.fin.red[tid] = cls;
    __syncthreads();
    for (int s = 128; s > 0; s >>= 1) {
        if (tid < s) u.fin.red[tid] += u.fin.red[tid + s];
        __syncthreads();
    }
    if (tid == 0 && u.fin.red[0] != 0.0f) atomicAdd((float*)&ws[OFF_CLS], u.fin.red[0]);
    __syncthreads();
    u.fin.red[tid] = reg;
    __syncthreads();
    for (int s = 128; s > 0; s >>= 1) {
        if (tid < s) u.fin.red[tid] += u.fin.red[tid + s];
        __syncthreads();
    }
    if (tid == 0) {
        if (u.fin.red[0] != 0.0f) atomicAdd((float*)&ws[OFF_REG], u.fin.red[0]);
        __threadfence();
        uint32_t old = atomicAdd(&ws[OFF_DONEA], 1u);
        if (old == Bn - 1) {
            float cls_tot = __uint_as_float(atomicAdd(&ws[OFF_CLS], 0u));
            float reg_tot = __uint_as_float(atomicAdd(&ws[OFF_REG], 0u));
            float cnt = (float)atomicAdd(&ws[OFF_COUNT], 0u);
            out[0] = cls_tot / cnt;
            out[1] = reg_tot / cnt;
        }
    }
}

extern "C" void kernel_launch(void* const* d_in, const int* in_sizes, int n_in,
                              void* d_out, int out_size, void* d_ws, size_t ws_size,
                              hipStream_t stream) {
    const float* anchors = (const float*)d_in[0];   // [B, N, 4]
    const float* logits  = (const float*)d_in[1];   // [B, A, H, W]
    const float* bregs   = (const float*)d_in[2];   // [B, 4A, H, W]
    const float* sizes   = (const float*)d_in[3];   // [B, 2]
    const float* targets = (const float*)d_in[4];   // [B, M, 4]
    float* out = (float*)d_out;
    uint32_t* ws = (uint32_t*)d_ws;

    k0_init<<<dim3((ZERO_WORDS + 255) / 256), dim3(256), 0, stream>>>(ws);
    k1_iou<<<dim3(NBLK, Bn), dim3(256), 0, stream>>>(anchors, targets, sizes, logits, ws);
    k2_resolve<<<dim3(NBLK, Bn), dim3(256), 0, stream>>>(anchors, targets, logits, bregs, ws, out);
}

// Round 9
// 288.932 us; speedup vs baseline: 1.0625x; 1.0625x over previous
//
#include <hip/hip_runtime.h>
#include <stdint.h>

#define Bn 4
#define An 3
#define Hn 168
#define Wn 256
#define Mn 32
#define HWn (Hn*Wn)
#define Nn (HWn*An)          // 129024
#define POS_CAP 8192
#define NPERIM 256
#define NPOSMAX 128
#define FG_THR 0.7f
#define BG_THR 0.3f
#define BETA (1.0f/9.0f)

#define NBLK 504             // blocks per image (APT=1: occupancy hides atomics, R6/R7)
#define NWAVES (NBLK*4)      // 2016 waves per image
#define TSEG_CAP 64          // per-wave deferred segment
#define NSEG_CAP 64          // per-wave certain-negative fallback segment
#define XSEG_CAP 256         // per-k2-block late-negative fallback segment
#define BIN_HOT 960          // bins >= BIN_HOT bucketed (top-64 bins ~2900 >> k_neg<=256)
#define NHOT 64
#define HB_CAP 256
#define CM_STRIDE 16         // 64B per CM word: atomicMax streams don't share lines

// ---- workspace layout (uint32 word offsets) ----
#define OFF_POSCNT 0            // Bn
#define OFF_DONEI  4            // Bn (per-image k2 ticket)
#define OFF_COUNT  8            // 1
#define OFF_CLS    9            // 1 (float bits)
#define OFF_REG    10           // 1 (float bits)
#define OFF_DONEA  11           // 1 (cross-image ticket)
#define OFF_BINCNT 16           // Bn*1024 -> 4112
#define OFF_BINBCE 4112         // Bn*1024 -> 8208
#define OFF_CM     8208         // Bn*32*CM_STRIDE = 2048 -> 10256 (global colmax, padded)
#define ZERO_WORDS 10256
#define OFF_WPCM   10256        // Bn*NWAVES*32 = 258048 -> 268304
#define OFF_TSEGC  268304       // Bn*NWAVES = 8064    -> 276368
#define OFF_NSEGC  276368       // Bn*NWAVES = 8064    -> 284432
#define OFF_XSEGC  284432       // Bn*NBLK = 2016      -> 286448
#define OFF_PLIST  286448       // Bn*POS_CAP*2 = 65536 -> 351984
#define OFF_HBUCK  351984       // Bn*NHOT*HB_CAP*2 = 131072 -> 483056
#define OFF_TSEG   483056       // Bn*NWAVES*TSEG_CAP*4 = 2064384 -> 2547440 (16B-aligned)
#define OFF_NSEG   2547440      // Bn*NWAVES*NSEG_CAP*2 = 1032192 -> 3579632
#define OFF_XSEG   3579632      // Bn*NBLK*XSEG_CAP*2 = 1032192 -> 4611824 (~18.4MB)

// ------------------- threefry2x32 (20 rounds) -------------------
__device__ __forceinline__ uint32_t rotl32(uint32_t v, int n) { return (v << n) | (v >> (32 - n)); }

__device__ __forceinline__ void tf2x32(uint32_t k0, uint32_t k1, uint32_t x0, uint32_t x1,
                                       uint32_t& o0, uint32_t& o1) {
    uint32_t k2 = k0 ^ k1 ^ 0x1BD11BDAu;
    x0 += k0; x1 += k1;
    x0 += x1; x1 = rotl32(x1, 13); x1 ^= x0;
    x0 += x1; x1 = rotl32(x1, 15); x1 ^= x0;
    x0 += x1; x1 = rotl32(x1, 26); x1 ^= x0;
    x0 += x1; x1 = rotl32(x1, 6);  x1 ^= x0;
    x0 += k1; x1 += k2 + 1u;
    x0 += x1; x1 = rotl32(x1, 17); x1 ^= x0;
    x0 += x1; x1 = rotl32(x1, 29); x1 ^= x0;
    x0 += x1; x1 = rotl32(x1, 16); x1 ^= x0;
    x0 += x1; x1 = rotl32(x1, 24); x1 ^= x0;
    x0 += k2; x1 += k0 + 2u;
    x0 += x1; x1 = rotl32(x1, 13); x1 ^= x0;
    x0 += x1; x1 = rotl32(x1, 15); x1 ^= x0;
    x0 += x1; x1 = rotl32(x1, 26); x1 ^= x0;
    x0 += x1; x1 = rotl32(x1, 6);  x1 ^= x0;
    x0 += k0; x1 += k1 + 3u;
    x0 += x1; x1 = rotl32(x1, 17); x1 ^= x0;
    x0 += x1; x1 = rotl32(x1, 29); x1 ^= x0;
    x0 += x1; x1 = rotl32(x1, 16); x1 ^= x0;
    x0 += x1; x1 = rotl32(x1, 24); x1 ^= x0;
    x0 += k1; x1 += k2 + 4u;
    x0 += x1; x1 = rotl32(x1, 13); x1 ^= x0;
    x0 += x1; x1 = rotl32(x1, 15); x1 ^= x0;
    x0 += x1; x1 = rotl32(x1, 26); x1 ^= x0;
    x0 += x1; x1 = rotl32(x1, 6);  x1 ^= x0;
    x0 += k2; x1 += k0 + 5u;
    o0 = x0; o1 = x1;
}

__device__ __forceinline__ uint32_t rng_m23(uint32_t k0, uint32_t k1, uint32_t i) {
    uint32_t o0, o1;
    tf2x32(k0, k1, 0u, i, o0, o1);
    return (o0 ^ o1) >> 9;
}

__device__ __forceinline__ uint32_t vload(const uint32_t* p) {
    return *(const volatile uint32_t*)p;
}

// device-scope visible 8B store (same-kernel cross-block consumption)
__device__ __forceinline__ void st64(uint2* p, uint2 v) {
    atomicExch((unsigned long long*)p,
               ((unsigned long long)v.y << 32) | (unsigned long long)v.x);
}

// ------------------- IoU (single definition) ------------
__device__ __forceinline__ float iou_one(float a0, float a1, float a2, float a3,
                                         float t0, float t1, float t2, float t3) {
    float xtl = fmaxf(a0, t0), ytl = fmaxf(a1, t1);
    float xrb = fminf(a2, t2), yrb = fminf(a3, t3);
    float iw = fmaxf(xrb - xtl + 1.0f, 0.0f);
    float ih = fmaxf(yrb - ytl + 1.0f, 0.0f);
    float inter = iw * ih;
    float area1 = (a2 - a0 + 1.0f) * (a3 - a1 + 1.0f);
    float area2 = (t2 - t0 + 1.0f) * (t3 - t1 + 1.0f);
    return inter * __builtin_amdgcn_rcpf(area1 + area2 - inter);
}

__device__ __forceinline__ float bce0(float l) {   // BCE(l, target=0)
    return fmaxf(l, 0.0f) + log1pf(expf(-fabsf(l)));
}

// ------------------- selection order (JAX top_k) -------------------
__device__ __forceinline__ bool sel_less(uint2 a, uint2 b) {
    return (a.x > b.x) || (a.x == b.x && a.y < b.y);
}

__device__ void bitonic_sort_shared(uint2* buf, int n) {   // n = pow2
    for (int k = 2; k <= n; k <<= 1) {
        for (int j = k >> 1; j > 0; j >>= 1) {
            for (int t = (int)threadIdx.x; t < n; t += (int)blockDim.x) {
                int ixj = t ^ j;
                if (ixj > t) {
                    uint2 x = buf[t], y = buf[ixj];
                    bool up = ((t & k) == 0);
                    bool sw = up ? sel_less(y, x) : sel_less(x, y);
                    if (sw) { buf[t] = y; buf[ixj] = x; }
                }
            }
            __syncthreads();
        }
    }
}

// =====================================================================================
// K0: zero control + bin counters/sums + CM.
// =====================================================================================
__global__ void __launch_bounds__(256) k0_init(uint32_t* __restrict__ ws) {
    int i = blockIdx.x * 256 + (int)threadIdx.x;
    if (i < ZERO_WORDS) ws[i] = 0u;
}

// =====================================================================================
// K1: IoU + categorize. One anchor/thread.
// Global colmax: block LDS reduce -> 32 fire-and-forget uint atomicMax into padded CM
// (exact for non-negative floats; no return dependency -> pipelined, ~504 ops/line).
// R6/R8 lesson encoded: NO per-block redundant CM re-reduce anywhere downstream.
// =====================================================================================
__global__ void __launch_bounds__(256) k1_iou(const float* __restrict__ anchors,
                                              const float* __restrict__ targets,
                                              const float* __restrict__ sizes,
                                              const float* __restrict__ logits,
                                              uint32_t* __restrict__ ws) {
    const int b = blockIdx.y, j = blockIdx.x, tid = threadIdx.x;
    const int wid = tid >> 6, lane = tid & 63;
    __shared__ float part[4][Mn];

    uint32_t key0, key1;
    tf2x32(0u, 42u, 0u, (uint32_t)b, key0, key1);

    const int i = j * 256 + tid;
    float4 av = ((const float4*)anchors)[b * Nn + i];

    float rowmax = -1.0f; int ori = 0; uint32_t tie = 0u;
    float mycm = 0.0f;   // lane t (t<32) ends holding wave colmax of target t
    #pragma unroll 4
    for (int t = 0; t < Mn; ++t) {
        float4 tv = ((const float4*)targets)[b * Mn + t];
        float io = iou_one(av.x, av.y, av.z, av.w, tv.x, tv.y, tv.z, tv.w);
        if (io > rowmax) { rowmax = io; ori = t; }
        float m0 = io;
        #pragma unroll
        for (int o = 32; o > 0; o >>= 1) m0 = fmaxf(m0, __shfl_xor(m0, o, 64));
        if (lane == t) mycm = m0;
        tie |= (io == m0) ? (1u << t) : 0u;
    }

    const int wimg = j * 4 + wid;
    if (lane < Mn) {
        ws[OFF_WPCM + ((size_t)b * NWAVES + wimg) * 32 + lane] = __float_as_uint(mycm);
        part[wid][lane] = mycm;
    }
    __syncthreads();
    if (tid < Mn) {
        float v = fmaxf(fmaxf(part[0][tid], part[1][tid]),
                        fmaxf(part[2][tid], part[3][tid]));
        atomicMax(&ws[OFF_CM + (b * 32 + tid) * CM_STRIDE], __float_as_uint(v));
    }

    const float sh = sizes[b * 2 + 0], sw = sizes[b * 2 + 1];
    unsigned long long lt_mask = (lane == 63) ? 0x7FFFFFFFFFFFFFFFull
                                              : ((1ull << lane) - 1ull);
    bool inside = (av.x >= 0.0f) && (av.y >= 0.0f) &&
                  (av.z <= sw - 1.0f) && (av.w <= sh - 1.0f);
    bool fg = rowmax >= FG_THR;
    bool bg = rowmax < BG_THR;
    bool posn   = inside && fg;
    bool defern = inside && !fg && (tie != 0u);
    bool negn   = inside && bg && (tie == 0u);
    uint32_t m = rng_m23(key0, key1, (uint32_t)i);

    const int a_ = i % An, hw_ = i / An;
    float lneg = 0.0f;
    if (negn) lneg = logits[(b * An + a_) * HWn + hw_];

    unsigned long long pmask = __ballot(posn);
    if (pmask) {
        int leader = __ffsll((long long)pmask) - 1;
        uint32_t bb = 0;
        if (lane == leader) bb = atomicAdd(&ws[OFF_POSCNT + b], (uint32_t)__popcll(pmask));
        bb = __shfl(bb, leader, 64);
        if (posn) {
            uint32_t p = bb + (uint32_t)__popcll(pmask & lt_mask);
            if (p < POS_CAP)
                ((uint2*)(ws + OFF_PLIST))[(size_t)b * POS_CAP + p] =
                    make_uint2(m, (uint32_t)i | ((uint32_t)ori << 17));
        }
    }
    unsigned long long dmask = __ballot(defern);
    if (defern) {
        uint32_t slot = (uint32_t)__popcll(dmask & lt_mask);
        ((uint4*)(ws + OFF_TSEG))[((size_t)b * NWAVES + wimg) * TSEG_CAP + slot] =
            make_uint4(tie, m,
                       (uint32_t)i | ((uint32_t)ori << 17) | (bg ? (1u << 22) : 0u), 0u);
    }
    unsigned long long nmask = __ballot(negn);
    if (negn) {
        uint32_t slot = (uint32_t)__popcll(nmask & lt_mask);
        ((uint2*)(ws + OFF_NSEG))[((size_t)b * NWAVES + wimg) * NSEG_CAP + slot] =
            make_uint2(m, (uint32_t)i);
        int bin = (int)(m >> 13);
        if (bin >= BIN_HOT) {
            uint32_t s2 = atomicAdd(&ws[OFF_BINCNT + (b << 10) + bin], 1u);   // returning (6%)
            if (s2 < HB_CAP)
                ((uint2*)(ws + OFF_HBUCK))[((size_t)b * NHOT + (bin - BIN_HOT)) * HB_CAP + s2] =
                    make_uint2(m, (uint32_t)i);
        } else {
            atomicAdd(&ws[OFF_BINCNT + (b << 10) + bin], 1u);                 // fire-and-forget
        }
        atomicAdd((float*)&ws[OFF_BINBCE + (b << 10) + bin], bce0(lneg));     // fire-and-forget
    }
    if (lane == 0) {
        ws[OFF_TSEGC + b * NWAVES + wimg] = (uint32_t)__popcll(dmask);
        ws[OFF_NSEGC + b * NWAVES + wimg] = (uint32_t)__popcll(nmask);
    }
}

// =====================================================================================
// K2: full grid (504 x 4). Per block: read CM (32 padded words, L2-hit) -> eqmask for
// own 4 waves -> resolve own deferred ties. Per-image ticket; last block per image runs
// the fused finalize (scan + sorts + losses + output). Cross-block same-kernel data via
// st64/atomics + threadfence (R8: verified absmax 0.0).
// =====================================================================================
__global__ void __launch_bounds__(256) k2_resolve(const float* __restrict__ anchors,
                                                  const float* __restrict__ targets,
                                                  const float* __restrict__ logits,
                                                  const float* __restrict__ bregs,
                                                  uint32_t* __restrict__ ws,
                                                  float* __restrict__ out) {
    const int b = blockIdx.y, j = blockIdx.x, tid = threadIdx.x;
    const int lane = tid & 63;
    __shared__ uint32_t cmb[Mn];
    __shared__ uint32_t eqs[4];
    __shared__ uint32_t cnts[4];
    __shared__ uint32_t sx_cnt, s_fcnt;
    __shared__ int s_last, s_bd, s_need;
    struct Fin { uint32_t csum[256]; uint2 buf[2048]; float red[256]; };
    __shared__ Fin u;

    if (tid < 4) { eqs[tid] = 0u; cnts[tid] = ws[OFF_TSEGC + b * NWAVES + j * 4 + tid]; }
    if (tid == 0) sx_cnt = 0u;
    if (tid < Mn) cmb[tid] = ws[OFF_CM + (b * 32 + tid) * CM_STRIDE];
    __syncthreads();
    const int total = (int)(cnts[0] + cnts[1] + cnts[2] + cnts[3]);

    if (total > 0) {
        // eqmask for this block's 4 k1-waves (512B WPCM read)
        if (tid < 128) {
            int lw = tid >> 5, t2 = tid & 31;
            uint32_t wv = ws[OFF_WPCM + ((size_t)b * NWAVES + j * 4 + lw) * 32 + t2];
            if (wv == cmb[t2]) atomicOr(&eqs[lw], 1u << t2);
        }
        __syncthreads();

        const uint32_t c0 = cnts[0], c1 = cnts[1], c2 = cnts[2], c3 = cnts[3];
        unsigned long long lt_mask = (lane == 63) ? 0x7FFFFFFFFFFFFFFFull
                                                  : ((1ull << lane) - 1ull);
        for (int f = tid; f < total; f += 256) {
            int lw, o;
            if ((uint32_t)f < c0)                { lw = 0; o = f; }
            else if ((uint32_t)f < c0 + c1)      { lw = 1; o = f - (int)c0; }
            else if ((uint32_t)f < c0 + c1 + c2) { lw = 2; o = f - (int)(c0 + c1); }
            else                                 { lw = 3; o = f - (int)(c0 + c1 + c2); }
            uint4 e = ((const uint4*)(ws + OFF_TSEG))
                          [((size_t)b * NWAVES + j * 4 + lw) * TSEG_CAP + o];
            int i = (int)(e.z & 0x1FFFFu);
            bool restored = (e.x & eqs[lw]) != 0u;

            unsigned long long rmask = __ballot(restored);
            if (rmask) {
                int leader = __ffsll((long long)rmask) - 1;
                uint32_t bb = 0;
                if (lane == leader) bb = atomicAdd(&ws[OFF_POSCNT + b], (uint32_t)__popcll(rmask));
                bb = __shfl(bb, leader, 64);
                if (restored) {
                    uint32_t p = bb + (uint32_t)__popcll(rmask & lt_mask);
                    if (p < POS_CAP)
                        st64(&((uint2*)(ws + OFF_PLIST))[(size_t)b * POS_CAP + p],
                             make_uint2(e.y, e.z & 0x3FFFFFu));
                }
            }
            if (!restored && (e.z & (1u << 22))) {   // late negative
                uint32_t m = e.y;
                int bin = (int)(m >> 13);
                if (bin >= BIN_HOT) {
                    uint32_t s2 = atomicAdd(&ws[OFF_BINCNT + (b << 10) + bin], 1u);
                    if (s2 < HB_CAP)
                        st64(&((uint2*)(ws + OFF_HBUCK))
                                 [((size_t)b * NHOT + (bin - BIN_HOT)) * HB_CAP + s2],
                             make_uint2(m, (uint32_t)i));
                } else {
                    atomicAdd(&ws[OFF_BINCNT + (b << 10) + bin], 1u);
                }
                int a = i % An, hw = i / An;
                float l = logits[(b * An + a) * HWn + hw];
                atomicAdd((float*)&ws[OFF_BINBCE + (b << 10) + bin], bce0(l));
                uint32_t xs = atomicAdd(&sx_cnt, 1u);    // LDS
                if (xs < XSEG_CAP)
                    st64(&((uint2*)(ws + OFF_XSEG))[((size_t)b * NBLK + j) * XSEG_CAP + xs],
                         make_uint2(m, (uint32_t)i));
            }
        }
    }
    __syncthreads();
    if (tid == 0) ws[OFF_XSEGC + b * NBLK + j] = sx_cnt;

    // ---- per-image ticket: last block runs the finalize ----
    __threadfence();
    __syncthreads();
    if (tid == 0) {
        uint32_t old = atomicAdd(&ws[OFF_DONEI + b], 1u);
        s_last = (old == (uint32_t)(NBLK - 1)) ? 1 : 0;
    }
    __syncthreads();
    if (!s_last) return;

    // ================= finalize for image b (256 threads) =================
    __threadfence();   // acquire
    float cls = 0.0f, reg = 0.0f;

    uint32_t c4[4];
    #pragma unroll
    for (int q = 0; q < 4; ++q) c4[q] = vload(ws + OFF_BINCNT + (b << 10) + 4 * tid + q);
    u.csum[tid] = c4[0] + c4[1] + c4[2] + c4[3];
    __syncthreads();
    for (int off = 1; off < 256; off <<= 1) {
        uint32_t mine = u.csum[tid];
        uint32_t add = (tid + off < 256) ? u.csum[tid + off] : 0u;
        __syncthreads();
        u.csum[tid] = mine + add;
        __syncthreads();
    }
    uint32_t pc = vload(ws + OFF_POSCNT + b);
    int num_pos = (pc < (uint32_t)NPOSMAX) ? (int)pc : NPOSMAX;
    int k_neg = NPERIM - num_pos;
    uint32_t total_n = u.csum[0];
    if (tid == 0 && (int)total_n < k_neg) { s_bd = -1; s_need = 0; }
    {
        uint32_t incl = u.csum[tid];
        uint32_t nxt = (tid < 255) ? u.csum[tid + 1] : 0u;
        if ((int)total_n >= k_neg && (int)incl >= k_neg && (int)nxt < k_neg) {
            int cum = (int)nxt, boundary = -1, needed = 0;
            #pragma unroll
            for (int q = 3; q >= 0; --q) {
                int c = (int)c4[q];
                if (cum + c >= k_neg) { boundary = 4 * tid + q; needed = k_neg - cum; break; }
                cum += c;
            }
            s_bd = boundary; s_need = needed;
        }
    }
    if (tid == 0) {
        int sel_negs = ((int)total_n < k_neg) ? (int)total_n : k_neg;
        atomicAdd(&ws[OFF_COUNT], (uint32_t)(num_pos + sel_negs));
    }
    __syncthreads();
    const int bd = s_bd, need = s_need;
    #pragma unroll
    for (int q = 0; q < 4; ++q) {
        int bin = 4 * tid + q;
        if (bin > bd) cls += __uint_as_float(vload(ws + OFF_BINBCE + (b << 10) + bin));
    }
    __syncthreads();

    if (need > 0) {
        int cnt;
        if (bd >= BIN_HOT) {
            cnt = (int)vload(ws + OFF_BINCNT + (b << 10) + bd);
            if (cnt > HB_CAP) cnt = HB_CAP;
            const uint2* bkt = (const uint2*)(ws + OFF_HBUCK) +
                               ((size_t)b * NHOT + (bd - BIN_HOT)) * HB_CAP;
            for (int t = tid; t < cnt; t += 256) u.buf[t] = bkt[t];
        } else {
            // fallback (probability ~0; correctness-only): gather bin==bd from segments
            if (tid == 0) s_fcnt = 0u;
            __syncthreads();
            for (int w = 0; w < NWAVES; ++w) {
                int cw = (int)vload(ws + OFF_NSEGC + b * NWAVES + w);
                const uint2* ns = (const uint2*)(ws + OFF_NSEG) +
                                  ((size_t)b * NWAVES + w) * NSEG_CAP;
                for (int idx = tid; idx < cw; idx += 256) {
                    uint2 e = ns[idx];
                    if ((int)(e.x >> 13) == bd) {
                        uint32_t q2 = atomicAdd(&s_fcnt, 1u);
                        if (q2 < 2048u) u.buf[q2] = e;
                    }
                }
            }
            for (int j2 = 0; j2 < NBLK; ++j2) {
                int cx = (int)vload(ws + OFF_XSEGC + b * NBLK + j2);
                if (cx > XSEG_CAP) cx = XSEG_CAP;
                const uint2* xs = (const uint2*)(ws + OFF_XSEG) +
                                  ((size_t)b * NBLK + j2) * XSEG_CAP;
                for (int idx = tid; idx < cx; idx += 256) {
                    uint2 e = xs[idx];
                    if ((int)(e.x >> 13) == bd) {
                        uint32_t q2 = atomicAdd(&s_fcnt, 1u);
                        if (q2 < 2048u) u.buf[q2] = e;
                    }
                }
            }
            __syncthreads();
            cnt = (int)s_fcnt; if (cnt > 2048) cnt = 2048;
        }
        int npad = 1; while (npad < cnt) npad <<= 1;
        for (int t = tid; t < npad; t += 256) if (t >= cnt) u.buf[t] = make_uint2(0u, 0xFFFFFFFFu);
        __syncthreads();
        bitonic_sort_shared(u.buf, npad);
        int sel = (need < cnt) ? need : cnt;
        for (int t = tid; t < sel; t += 256) {
            int i = (int)u.buf[t].y;
            int a = i % An, hw = i / An;
            float l = logits[(b * An + a) * HWn + hw];
            cls += bce0(l);
        }
    }
    __syncthreads();

    // positives
    {
        int pci = (pc < (uint32_t)POS_CAP) ? (int)pc : POS_CAP;
        const uint2* plist = (const uint2*)(ws + OFF_PLIST) + (size_t)b * POS_CAP;
        int psel = (pci < NPOSMAX) ? pci : NPOSMAX;
        bool use_buf = false;
        if (pci > NPOSMAX) {
            int n = (pci < 2048) ? pci : 2048;
            for (int t = tid; t < n; t += 256) u.buf[t] = plist[t];
            int npad = 1; while (npad < n) npad <<= 1;
            for (int t = tid; t < npad; t += 256) if (t >= n) u.buf[t] = make_uint2(0u, 0xFFFFFFFFu);
            __syncthreads();
            bitonic_sort_shared(u.buf, npad);
            use_buf = true;
            psel = (NPOSMAX < n) ? NPOSMAX : n;
        }
        for (int t = tid; t < psel; t += 256) {
            uint32_t packed = use_buf ? u.buf[t].y : plist[t].y;
            int i = (int)(packed & 0x1FFFFu);
            int orit = (int)((packed >> 17) & 0x1Fu);
            int a = i % An, hw = i / An;
            float l = logits[(b * An + a) * HWn + hw];
            cls += fmaxf(l, 0.0f) - l + log1pf(expf(-fabsf(l)));   // BCE(l,1)
            float4 avx = ((const float4*)anchors)[b * Nn + i];
            float4 tv = ((const float4*)targets)[b * Mn + orit];
            float aws = avx.z - avx.x + 1.0f, ahs = avx.w - avx.y + 1.0f;
            float axc = avx.x + 0.5f * aws, ayc = avx.y + 0.5f * ahs;
            float tws = tv.z - tv.x + 1.0f, ths = tv.w - tv.y + 1.0f;
            float txc = tv.x + 0.5f * tws, tyc = tv.y + 0.5f * ths;
            float off0 = (txc - axc) / aws;
            float off1 = (tyc - ayc) / ahs;
            float off2 = logf(tws / aws);
            float off3 = logf(ths / ahs);
            float br0 = bregs[(b * 12 + a * 4 + 0) * HWn + hw];
            float br1 = bregs[(b * 12 + a * 4 + 1) * HWn + hw];
            float br2 = bregs[(b * 12 + a * 4 + 2) * HWn + hw];
            float br3 = bregs[(b * 12 + a * 4 + 3) * HWn + hw];
            float d;
            d = fabsf(br0 - off0); reg += (d < BETA) ? 0.5f * d * d / BETA : d - 0.5f * BETA;
            d = fabsf(br1 - off1); reg += (d < BETA) ? 0.5f * d * d / BETA : d - 0.5f * BETA;
            d = fabsf(br2 - off2); reg += (d < BETA) ? 0.5f * d * d / BETA : d - 0.5f * BETA;
            d = fabsf(br3 - off3); reg += (d < BETA) ? 0.5f * d * d / BETA : d - 0.5f * BETA;
        }
    }
    __syncthreads();

    // reductions + cross-image epilogue
    u.red[tid] = cls;
    __syncthreads();
    for (int s = 128; s > 0; s >>= 1) {
        if (tid < s) u.red[tid] += u.red[tid + s];
        __syncthreads();
    }
    if (tid == 0 && u.red[0] != 0.0f) atomicAdd((float*)&ws[OFF_CLS], u.red[0]);
    __syncthreads();
    u.red[tid] = reg;
    __syncthreads();
    for (int s = 128; s > 0; s >>= 1) {
        if (tid < s) u.red[tid] += u.red[tid + s];
        __syncthreads();
    }
    if (tid == 0) {
        if (u.red[0] != 0.0f) atomicAdd((float*)&ws[OFF_REG], u.red[0]);
        __threadfence();
        uint32_t old = atomicAdd(&ws[OFF_DONEA], 1u);
        if (old == Bn - 1) {
            float cls_tot = __uint_as_float(atomicAdd(&ws[OFF_CLS], 0u));
            float reg_tot = __uint_as_float(atomicAdd(&ws[OFF_REG], 0u));
            float cnt = (float)atomicAdd(&ws[OFF_COUNT], 0u);
            out[0] = cls_tot / cnt;
            out[1] = reg_tot / cnt;
        }
    }
}

extern "C" void kernel_launch(void* const* d_in, const int* in_sizes, int n_in,
                              void* d_out, int out_size, void* d_ws, size_t ws_size,
                              hipStream_t stream) {
    const float* anchors = (const float*)d_in[0];   // [B, N, 4]
    const float* logits  = (const float*)d_in[1];   // [B, A, H, W]
    const float* bregs   = (const float*)d_in[2];   // [B, 4A, H, W]
    const float* sizes   = (const float*)d_in[3];   // [B, 2]
    const float* targets = (const float*)d_in[4];   // [B, M, 4]
    float* out = (float*)d_out;
    uint32_t* ws = (uint32_t*)d_ws;

    k0_init<<<dim3((ZERO_WORDS + 255) / 256), dim3(256), 0, stream>>>(ws);
    k1_iou<<<dim3(NBLK, Bn), dim3(256), 0, stream>>>(anchors, targets, sizes, logits, ws);
    k2_resolve<<<dim3(NBLK, Bn), dim3(256), 0, stream>>>(anchors, targets, logits, bregs, ws, out);
}

// Round 10
// 172.348 us; speedup vs baseline: 1.7813x; 1.6764x over previous
//
#include <hip/hip_runtime.h>
#include <stdint.h>

#define Bn 4
#define An 3
#define Hn 168
#define Wn 256
#define Mn 32
#define HWn (Hn*Wn)
#define Nn (HWn*An)          // 129024
#define POS_CAP 8192
#define NPERIM 256
#define NPOSMAX 128
#define FG_THR 0.7f
#define BG_THR 0.3f
#define BETA (1.0f/9.0f)

#define NBLK 504             // blocks per image (APT=1: occupancy hides atomics)
#define NWAVES (NBLK*4)      // 2016 waves per image
#define TSEG_CAP 64          // per-wave deferred segment
#define NSEG_CAP 64          // per-wave certain-negative fallback segment
#define XSEG_CAP 256         // per-k2-block late-negative fallback segment
#define BIN_HOT 960          // bins >= BIN_HOT bucketed (top-64 bins ~2900 >> k_neg<=256)
#define NHOT 64
#define HB_CAP 256
#define CM_STRIDE 16         // 64B per CM word: atomicMax streams don't share lines

// ---- workspace layout (uint32 word offsets) ----
#define OFF_POSCNT 0            // Bn
#define OFF_COUNT  8            // 1
#define OFF_CLS    9            // 1 (float bits)
#define OFF_REG    10           // 1 (float bits)
#define OFF_DONEA  11           // 1 (cross-image ticket, k3 only: 4 blocks)
#define OFF_BINCNT 16           // Bn*1024 -> 4112
#define OFF_BINBCE 4112         // Bn*1024 -> 8208
#define OFF_CM     8208         // Bn*32*CM_STRIDE = 2048 -> 10256
#define ZERO_WORDS 10256
#define OFF_WPCM   10256        // Bn*NWAVES*32 = 258048 -> 268304
#define OFF_TSEGC  268304       // Bn*NWAVES = 8064    -> 276368
#define OFF_NSEGC  276368       // Bn*NWAVES = 8064    -> 284432
#define OFF_XSEGC  284432       // Bn*NBLK = 2016      -> 286448
#define OFF_PLIST  286448       // Bn*POS_CAP*2 = 65536 -> 351984
#define OFF_HBUCK  351984       // Bn*NHOT*HB_CAP*2 = 131072 -> 483056
#define OFF_TSEG   483056       // Bn*NWAVES*TSEG_CAP*4 = 2064384 -> 2547440
#define OFF_NSEG   2547440      // Bn*NWAVES*NSEG_CAP*2 = 1032192 -> 3579632
#define OFF_XSEG   3579632      // Bn*NBLK*XSEG_CAP*2 = 1032192 -> 4611824 (~18.4MB)

// ------------------- threefry2x32 (20 rounds) -------------------
__device__ __forceinline__ uint32_t rotl32(uint32_t v, int n) { return (v << n) | (v >> (32 - n)); }

__device__ __forceinline__ void tf2x32(uint32_t k0, uint32_t k1, uint32_t x0, uint32_t x1,
                                       uint32_t& o0, uint32_t& o1) {
    uint32_t k2 = k0 ^ k1 ^ 0x1BD11BDAu;
    x0 += k0; x1 += k1;
    x0 += x1; x1 = rotl32(x1, 13); x1 ^= x0;
    x0 += x1; x1 = rotl32(x1, 15); x1 ^= x0;
    x0 += x1; x1 = rotl32(x1, 26); x1 ^= x0;
    x0 += x1; x1 = rotl32(x1, 6);  x1 ^= x0;
    x0 += k1; x1 += k2 + 1u;
    x0 += x1; x1 = rotl32(x1, 17); x1 ^= x0;
    x0 += x1; x1 = rotl32(x1, 29); x1 ^= x0;
    x0 += x1; x1 = rotl32(x1, 16); x1 ^= x0;
    x0 += x1; x1 = rotl32(x1, 24); x1 ^= x0;
    x0 += k2; x1 += k0 + 2u;
    x0 += x1; x1 = rotl32(x1, 13); x1 ^= x0;
    x0 += x1; x1 = rotl32(x1, 15); x1 ^= x0;
    x0 += x1; x1 = rotl32(x1, 26); x1 ^= x0;
    x0 += x1; x1 = rotl32(x1, 6);  x1 ^= x0;
    x0 += k0; x1 += k1 + 3u;
    x0 += x1; x1 = rotl32(x1, 17); x1 ^= x0;
    x0 += x1; x1 = rotl32(x1, 29); x1 ^= x0;
    x0 += x1; x1 = rotl32(x1, 16); x1 ^= x0;
    x0 += x1; x1 = rotl32(x1, 24); x1 ^= x0;
    x0 += k1; x1 += k2 + 4u;
    x0 += x1; x1 = rotl32(x1, 13); x1 ^= x0;
    x0 += x1; x1 = rotl32(x1, 15); x1 ^= x0;
    x0 += x1; x1 = rotl32(x1, 26); x1 ^= x0;
    x0 += x1; x1 = rotl32(x1, 6);  x1 ^= x0;
    x0 += k2; x1 += k0 + 5u;
    o0 = x0; o1 = x1;
}

__device__ __forceinline__ uint32_t rng_m23(uint32_t k0, uint32_t k1, uint32_t i) {
    uint32_t o0, o1;
    tf2x32(k0, k1, 0u, i, o0, o1);
    return (o0 ^ o1) >> 9;
}

// ------------------- IoU (single definition) ------------
__device__ __forceinline__ float iou_one(float a0, float a1, float a2, float a3,
                                         float t0, float t1, float t2, float t3) {
    float xtl = fmaxf(a0, t0), ytl = fmaxf(a1, t1);
    float xrb = fminf(a2, t2), yrb = fminf(a3, t3);
    float iw = fmaxf(xrb - xtl + 1.0f, 0.0f);
    float ih = fmaxf(yrb - ytl + 1.0f, 0.0f);
    float inter = iw * ih;
    float area1 = (a2 - a0 + 1.0f) * (a3 - a1 + 1.0f);
    float area2 = (t2 - t0 + 1.0f) * (t3 - t1 + 1.0f);
    return inter * __builtin_amdgcn_rcpf(area1 + area2 - inter);
}

__device__ __forceinline__ float bce0(float l) {   // BCE(l, target=0)
    return fmaxf(l, 0.0f) + log1pf(expf(-fabsf(l)));
}

// ------------------- selection order (JAX top_k) -------------------
__device__ __forceinline__ bool sel_less(uint2 a, uint2 b) {
    return (a.x > b.x) || (a.x == b.x && a.y < b.y);
}

__device__ void bitonic_sort_shared(uint2* buf, int n) {   // n = pow2
    for (int k = 2; k <= n; k <<= 1) {
        for (int j = k >> 1; j > 0; j >>= 1) {
            for (int t = (int)threadIdx.x; t < n; t += (int)blockDim.x) {
                int ixj = t ^ j;
                if (ixj > t) {
                    uint2 x = buf[t], y = buf[ixj];
                    bool up = ((t & k) == 0);
                    bool sw = up ? sel_less(y, x) : sel_less(x, y);
                    if (sw) { buf[t] = y; buf[ixj] = x; }
                }
            }
            __syncthreads();
        }
    }
}

// =====================================================================================
// K0: zero control + bin counters/sums + CM.
// =====================================================================================
__global__ void __launch_bounds__(256) k0_init(uint32_t* __restrict__ ws) {
    int i = blockIdx.x * 256 + (int)threadIdx.x;
    if (i < ZERO_WORDS) ws[i] = 0u;
}

// =====================================================================================
// K1: IoU + categorize (R9's verified kernel, unchanged).
// Global colmax: 32 fire-and-forget atomicMax/block into padded CM (exact for
// non-negative floats). NO fences, NO tickets (R8/R9 lesson: in-kernel device-scope
// release = 2016 L2 writebacks = 180us; kernel boundary does it once for ~10us).
// =====================================================================================
__global__ void __launch_bounds__(256) k1_iou(const float* __restrict__ anchors,
                                              const float* __restrict__ targets,
                                              const float* __restrict__ sizes,
                                              const float* __restrict__ logits,
                                              uint32_t* __restrict__ ws) {
    const int b = blockIdx.y, j = blockIdx.x, tid = threadIdx.x;
    const int wid = tid >> 6, lane = tid & 63;
    __shared__ float part[4][Mn];

    uint32_t key0, key1;
    tf2x32(0u, 42u, 0u, (uint32_t)b, key0, key1);

    const int i = j * 256 + tid;
    float4 av = ((const float4*)anchors)[b * Nn + i];

    float rowmax = -1.0f; int ori = 0; uint32_t tie = 0u;
    float mycm = 0.0f;   // lane t (t<32) ends holding wave colmax of target t
    #pragma unroll 4
    for (int t = 0; t < Mn; ++t) {
        float4 tv = ((const float4*)targets)[b * Mn + t];
        float io = iou_one(av.x, av.y, av.z, av.w, tv.x, tv.y, tv.z, tv.w);
        if (io > rowmax) { rowmax = io; ori = t; }
        float m0 = io;
        #pragma unroll
        for (int o = 32; o > 0; o >>= 1) m0 = fmaxf(m0, __shfl_xor(m0, o, 64));
        if (lane == t) mycm = m0;
        tie |= (io == m0) ? (1u << t) : 0u;
    }

    const int wimg = j * 4 + wid;
    if (lane < Mn) {
        ws[OFF_WPCM + ((size_t)b * NWAVES + wimg) * 32 + lane] = __float_as_uint(mycm);
        part[wid][lane] = mycm;
    }
    __syncthreads();
    if (tid < Mn) {
        float v = fmaxf(fmaxf(part[0][tid], part[1][tid]),
                        fmaxf(part[2][tid], part[3][tid]));
        atomicMax(&ws[OFF_CM + (b * 32 + tid) * CM_STRIDE], __float_as_uint(v));
    }

    const float sh = sizes[b * 2 + 0], sw = sizes[b * 2 + 1];
    unsigned long long lt_mask = (lane == 63) ? 0x7FFFFFFFFFFFFFFFull
                                              : ((1ull << lane) - 1ull);
    bool inside = (av.x >= 0.0f) && (av.y >= 0.0f) &&
                  (av.z <= sw - 1.0f) && (av.w <= sh - 1.0f);
    bool fg = rowmax >= FG_THR;
    bool bg = rowmax < BG_THR;
    bool posn   = inside && fg;
    bool defern = inside && !fg && (tie != 0u);
    bool negn   = inside && bg && (tie == 0u);
    uint32_t m = rng_m23(key0, key1, (uint32_t)i);

    const int a_ = i % An, hw_ = i / An;
    float lneg = 0.0f;
    if (negn) lneg = logits[(b * An + a_) * HWn + hw_];

    unsigned long long pmask = __ballot(posn);
    if (pmask) {
        int leader = __ffsll((long long)pmask) - 1;
        uint32_t bb = 0;
        if (lane == leader) bb = atomicAdd(&ws[OFF_POSCNT + b], (uint32_t)__popcll(pmask));
        bb = __shfl(bb, leader, 64);
        if (posn) {
            uint32_t p = bb + (uint32_t)__popcll(pmask & lt_mask);
            if (p < POS_CAP)
                ((uint2*)(ws + OFF_PLIST))[(size_t)b * POS_CAP + p] =
                    make_uint2(m, (uint32_t)i | ((uint32_t)ori << 17));
        }
    }
    unsigned long long dmask = __ballot(defern);
    if (defern) {
        uint32_t slot = (uint32_t)__popcll(dmask & lt_mask);
        ((uint4*)(ws + OFF_TSEG))[((size_t)b * NWAVES + wimg) * TSEG_CAP + slot] =
            make_uint4(tie, m,
                       (uint32_t)i | ((uint32_t)ori << 17) | (bg ? (1u << 22) : 0u), 0u);
    }
    unsigned long long nmask = __ballot(negn);
    if (negn) {
        uint32_t slot = (uint32_t)__popcll(nmask & lt_mask);
        ((uint2*)(ws + OFF_NSEG))[((size_t)b * NWAVES + wimg) * NSEG_CAP + slot] =
            make_uint2(m, (uint32_t)i);
        int bin = (int)(m >> 13);
        if (bin >= BIN_HOT) {
            uint32_t s2 = atomicAdd(&ws[OFF_BINCNT + (b << 10) + bin], 1u);   // returning (6%)
            if (s2 < HB_CAP)
                ((uint2*)(ws + OFF_HBUCK))[((size_t)b * NHOT + (bin - BIN_HOT)) * HB_CAP + s2] =
                    make_uint2(m, (uint32_t)i);
        } else {
            atomicAdd(&ws[OFF_BINCNT + (b << 10) + bin], 1u);                 // fire-and-forget
        }
        atomicAdd((float*)&ws[OFF_BINBCE + (b << 10) + bin], bce0(lneg));     // fire-and-forget
    }
    if (lane == 0) {
        ws[OFF_TSEGC + b * NWAVES + wimg] = (uint32_t)__popcll(dmask);
        ws[OFF_NSEGC + b * NWAVES + wimg] = (uint32_t)__popcll(nmask);
    }
}

// =====================================================================================
// K2: lightweight distributed tie-resolve (R7 structure: was fast). Reads CM (128B,
// L2-hit) + own 4 waves' WPCM (512B) -> eqmasks -> resolves ~26 entries. Plain stores;
// the k2->k3 kernel boundary provides visibility. No fence, no ticket.
// =====================================================================================
__global__ void __launch_bounds__(256) k2_resolve(const float* __restrict__ logits,
                                                  uint32_t* __restrict__ ws) {
    const int b = blockIdx.y, j = blockIdx.x, tid = threadIdx.x;
    const int lane = tid & 63;
    __shared__ uint32_t cmb[Mn];
    __shared__ uint32_t eqs[4];
    __shared__ uint32_t cnts[4];
    __shared__ uint32_t sx_cnt;

    if (tid < 4) { eqs[tid] = 0u; cnts[tid] = ws[OFF_TSEGC + b * NWAVES + j * 4 + tid]; }
    if (tid == 0) sx_cnt = 0u;
    if (tid < Mn) cmb[tid] = ws[OFF_CM + (b * 32 + tid) * CM_STRIDE];
    __syncthreads();
    const int total = (int)(cnts[0] + cnts[1] + cnts[2] + cnts[3]);
    if (total > 0) {
        if (tid < 128) {
            int lw = tid >> 5, t2 = tid & 31;
            uint32_t wv = ws[OFF_WPCM + ((size_t)b * NWAVES + j * 4 + lw) * 32 + t2];
            if (wv == cmb[t2]) atomicOr(&eqs[lw], 1u << t2);
        }
        __syncthreads();

        const uint32_t c0 = cnts[0], c1 = cnts[1], c2 = cnts[2], c3 = cnts[3];
        unsigned long long lt_mask = (lane == 63) ? 0x7FFFFFFFFFFFFFFFull
                                                  : ((1ull << lane) - 1ull);
        for (int f = tid; f < total; f += 256) {
            int lw, o;
            if ((uint32_t)f < c0)                { lw = 0; o = f; }
            else if ((uint32_t)f < c0 + c1)      { lw = 1; o = f - (int)c0; }
            else if ((uint32_t)f < c0 + c1 + c2) { lw = 2; o = f - (int)(c0 + c1); }
            else                                 { lw = 3; o = f - (int)(c0 + c1 + c2); }
            uint4 e = ((const uint4*)(ws + OFF_TSEG))
                          [((size_t)b * NWAVES + j * 4 + lw) * TSEG_CAP + o];
            int i = (int)(e.z & 0x1FFFFu);
            bool restored = (e.x & eqs[lw]) != 0u;

            unsigned long long rmask = __ballot(restored);
            if (rmask) {
                int leader = __ffsll((long long)rmask) - 1;
                uint32_t bb = 0;
                if (lane == leader) bb = atomicAdd(&ws[OFF_POSCNT + b], (uint32_t)__popcll(rmask));
                bb = __shfl(bb, leader, 64);
                if (restored) {
                    uint32_t p = bb + (uint32_t)__popcll(rmask & lt_mask);
                    if (p < POS_CAP)
                        ((uint2*)(ws + OFF_PLIST))[(size_t)b * POS_CAP + p] =
                            make_uint2(e.y, e.z & 0x3FFFFFu);   // strip bg bit
                }
            }
            if (!restored && (e.z & (1u << 22))) {   // late negative
                uint32_t m = e.y;
                int bin = (int)(m >> 13);
                if (bin >= BIN_HOT) {
                    uint32_t s2 = atomicAdd(&ws[OFF_BINCNT + (b << 10) + bin], 1u);
                    if (s2 < HB_CAP)
                        ((uint2*)(ws + OFF_HBUCK))
                            [((size_t)b * NHOT + (bin - BIN_HOT)) * HB_CAP + s2] =
                                make_uint2(m, (uint32_t)i);
                } else {
                    atomicAdd(&ws[OFF_BINCNT + (b << 10) + bin], 1u);
                }
                int a = i % An, hw = i / An;
                float l = logits[(b * An + a) * HWn + hw];
                atomicAdd((float*)&ws[OFF_BINBCE + (b << 10) + bin], bce0(l));
                uint32_t xs = atomicAdd(&sx_cnt, 1u);    // LDS
                if (xs < XSEG_CAP)
                    ((uint2*)(ws + OFF_XSEG))[((size_t)b * NBLK + j) * XSEG_CAP + xs] =
                        make_uint2(m, (uint32_t)i);
            }
        }
    }
    __syncthreads();
    if (tid == 0) ws[OFF_XSEGC + b * NBLK + j] = sx_cnt;
}

// =====================================================================================
// K3: per-image finalize, 1024 threads, 1 block/image (R5 structure: small fetches).
// =====================================================================================
__global__ void __launch_bounds__(1024) k3_final(const float* __restrict__ anchors,
                                                 const float* __restrict__ targets,
                                                 const float* __restrict__ logits,
                                                 const float* __restrict__ bregs,
                                                 uint32_t* __restrict__ ws,
                                                 float* __restrict__ out) {
    const int b = blockIdx.x, tid = threadIdx.x;
    __shared__ uint32_t csum[1024];
    __shared__ uint2 buf[2048];
    __shared__ float fred[1024];
    __shared__ int s_bd, s_need;
    __shared__ uint32_t s_fcnt;
    float cls = 0.0f, reg = 0.0f;

    // ---- suffix scan of bin counts (bin == tid) ----
    csum[tid] = ws[OFF_BINCNT + (b << 10) + tid];
    __syncthreads();
    for (int off = 1; off < 1024; off <<= 1) {
        uint32_t v = csum[tid];
        uint32_t add = (tid + off < 1024) ? csum[tid + off] : 0u;
        __syncthreads();
        csum[tid] = v + add;
        __syncthreads();
    }
    uint32_t pc = ws[OFF_POSCNT + b];            // final (incl. restored)
    int num_pos = (pc < (uint32_t)NPOSMAX) ? (int)pc : NPOSMAX;
    int k_neg = NPERIM - num_pos;
    uint32_t total = csum[0];
    if (tid == 0 && (int)total < k_neg) { s_bd = -1; s_need = 0; }
    {
        uint32_t inclv = csum[tid];
        uint32_t nxt = (tid < 1023) ? csum[tid + 1] : 0u;
        if ((int)total >= k_neg && (int)inclv >= k_neg && (int)nxt < k_neg) {
            s_bd = tid; s_need = k_neg - (int)nxt;
        }
    }
    if (tid == 0) {
        int sel_negs = ((int)total < k_neg) ? (int)total : k_neg;
        atomicAdd(&ws[OFF_COUNT], (uint32_t)(num_pos + sel_negs));
    }
    __syncthreads();
    const int bd = s_bd, need = s_need;
    if ((int)tid > bd)
        cls += __uint_as_float(ws[OFF_BINBCE + (b << 10) + tid]);
    __syncthreads();

    // ---- boundary bin: sort, take top-`need` ----
    if (need > 0) {
        int cnt;
        if (bd >= BIN_HOT) {
            cnt = (int)ws[OFF_BINCNT + (b << 10) + bd];
            if (cnt > HB_CAP) cnt = HB_CAP;
            const uint2* bkt = (const uint2*)(ws + OFF_HBUCK) +
                               ((size_t)b * NHOT + (bd - BIN_HOT)) * HB_CAP;
            for (int t = tid; t < cnt; t += 1024) buf[t] = bkt[t];
        } else {
            // fallback (probability ~0; correctness-only): gather bin==bd from segments
            if (tid == 0) s_fcnt = 0u;
            __syncthreads();
            for (int w = tid >> 6; w < NWAVES; w += 16) {     // 16 waves scan in parallel
                int cw = (int)ws[OFF_NSEGC + b * NWAVES + w];
                const uint2* ns = (const uint2*)(ws + OFF_NSEG) +
                                  ((size_t)b * NWAVES + w) * NSEG_CAP;
                for (int idx = (tid & 63); idx < cw; idx += 64) {
                    uint2 e = ns[idx];
                    if ((int)(e.x >> 13) == bd) {
                        uint32_t q2 = atomicAdd(&s_fcnt, 1u);
                        if (q2 < 2048u) buf[q2] = e;
                    }
                }
            }
            for (int j2 = tid >> 6; j2 < NBLK; j2 += 16) {
                int cx = (int)ws[OFF_XSEGC + b * NBLK + j2];
                if (cx > XSEG_CAP) cx = XSEG_CAP;
                const uint2* xs = (const uint2*)(ws + OFF_XSEG) +
                                  ((size_t)b * NBLK + j2) * XSEG_CAP;
                for (int idx = (tid & 63); idx < cx; idx += 64) {
                    uint2 e = xs[idx];
                    if ((int)(e.x >> 13) == bd) {
                        uint32_t q2 = atomicAdd(&s_fcnt, 1u);
                        if (q2 < 2048u) buf[q2] = e;
                    }
                }
            }
            __syncthreads();
            cnt = (int)s_fcnt; if (cnt > 2048) cnt = 2048;
        }
        int npad = 1; while (npad < cnt) npad <<= 1;
        for (int t = tid; t < npad; t += 1024) if (t >= cnt) buf[t] = make_uint2(0u, 0xFFFFFFFFu);
        __syncthreads();
        bitonic_sort_shared(buf, npad);
        int sel = (need < cnt) ? need : cnt;
        for (int t = tid; t < sel; t += 1024) {
            int i = (int)buf[t].y;
            int a = i % An, hw = i / An;
            float l = logits[(b * An + a) * HWn + hw];
            cls += bce0(l);
        }
    }
    __syncthreads();

    // ---- positives ----
    {
        int pci = (pc < (uint32_t)POS_CAP) ? (int)pc : POS_CAP;
        const uint2* plist = (const uint2*)(ws + OFF_PLIST) + (size_t)b * POS_CAP;
        int psel = (pci < NPOSMAX) ? pci : NPOSMAX;
        bool use_buf = false;
        if (pci > NPOSMAX) {
            int n = (pci < 2048) ? pci : 2048;
            for (int t = tid; t < n; t += 1024) buf[t] = plist[t];
            int npad = 1; while (npad < n) npad <<= 1;
            for (int t = tid; t < npad; t += 1024) if (t >= n) buf[t] = make_uint2(0u, 0xFFFFFFFFu);
            __syncthreads();
            bitonic_sort_shared(buf, npad);
            use_buf = true;
            psel = (NPOSMAX < n) ? NPOSMAX : n;
        }
        for (int t = tid; t < psel; t += 1024) {
            uint32_t packed = use_buf ? buf[t].y : plist[t].y;
            int i = (int)(packed & 0x1FFFFu);
            int orit = (int)((packed >> 17) & 0x1Fu);
            int a = i % An, hw = i / An;
            float l = logits[(b * An + a) * HWn + hw];
            cls += fmaxf(l, 0.0f) - l + log1pf(expf(-fabsf(l)));   // BCE(l,1)
            float4 avx = ((const float4*)anchors)[b * Nn + i];
            float4 tv = ((const float4*)targets)[b * Mn + orit];
            float aws = avx.z - avx.x + 1.0f, ahs = avx.w - avx.y + 1.0f;
            float axc = avx.x + 0.5f * aws, ayc = avx.y + 0.5f * ahs;
            float tws = tv.z - tv.x + 1.0f, ths = tv.w - tv.y + 1.0f;
            float txc = tv.x + 0.5f * tws, tyc = tv.y + 0.5f * ths;
            float off0 = (txc - axc) / aws;
            float off1 = (tyc - ayc) / ahs;
            float off2 = logf(tws / aws);
            float off3 = logf(ths / ahs);
            float br0 = bregs[(b * 12 + a * 4 + 0) * HWn + hw];
            float br1 = bregs[(b * 12 + a * 4 + 1) * HWn + hw];
            float br2 = bregs[(b * 12 + a * 4 + 2) * HWn + hw];
            float br3 = bregs[(b * 12 + a * 4 + 3) * HWn + hw];
            float d;
            d = fabsf(br0 - off0); reg += (d < BETA) ? 0.5f * d * d / BETA : d - 0.5f * BETA;
            d = fabsf(br1 - off1); reg += (d < BETA) ? 0.5f * d * d / BETA : d - 0.5f * BETA;
            d = fabsf(br2 - off2); reg += (d < BETA) ? 0.5f * d * d / BETA : d - 0.5f * BETA;
            d = fabsf(br3 - off3); reg += (d < BETA) ? 0.5f * d * d / BETA : d - 0.5f * BETA;
        }
    }

    // ---- reductions + cross-image epilogue ----
    fred[tid] = cls;
    __syncthreads();
    for (int s = 512; s > 0; s >>= 1) {
        if (tid < s) fred[tid] += fred[tid + s];
        __syncthreads();
    }
    if (tid == 0 && fred[0] != 0.0f) atomicAdd((float*)&ws[OFF_CLS], fred[0]);
    __syncthreads();
    fred[tid] = reg;
    __syncthreads();
    for (int s = 512; s > 0; s >>= 1) {
        if (tid < s) fred[tid] += fred[tid + s];
        __syncthreads();
    }
    if (tid == 0) {
        if (fred[0] != 0.0f) atomicAdd((float*)&ws[OFF_REG], fred[0]);
        __threadfence();
        uint32_t old = atomicAdd(&ws[OFF_DONEA], 1u);
        if (old == Bn - 1) {
            float cls_tot = __uint_as_float(atomicAdd(&ws[OFF_CLS], 0u));
            float reg_tot = __uint_as_float(atomicAdd(&ws[OFF_REG], 0u));
            float cnt = (float)atomicAdd(&ws[OFF_COUNT], 0u);
            out[0] = cls_tot / cnt;
            out[1] = reg_tot / cnt;
        }
    }
}

extern "C" void kernel_launch(void* const* d_in, const int* in_sizes, int n_in,
                              void* d_out, int out_size, void* d_ws, size_t ws_size,
                              hipStream_t stream) {
    const float* anchors = (const float*)d_in[0];   // [B, N, 4]
    const float* logits  = (const float*)d_in[1];   // [B, A, H, W]
    const float* bregs   = (const float*)d_in[2];   // [B, 4A, H, W]
    const float* sizes   = (const float*)d_in[3];   // [B, 2]
    const float* targets = (const float*)d_in[4];   // [B, M, 4]
    float* out = (float*)d_out;
    uint32_t* ws = (uint32_t*)d_ws;

    k0_init<<<dim3((ZERO_WORDS + 255) / 256), dim3(256), 0, stream>>>(ws);
    k1_iou<<<dim3(NBLK, Bn), dim3(256), 0, stream>>>(anchors, targets, sizes, logits, ws);
    k2_resolve<<<dim3(NBLK, Bn), dim3(256), 0, stream>>>(logits, ws);
    k3_final<<<dim3(Bn), dim3(1024), 0, stream>>>(anchors, targets, logits, bregs, ws, out);
}

// Round 11
// 154.798 us; speedup vs baseline: 1.9832x; 1.1134x over previous
//
#include <hip/hip_runtime.h>
#include <stdint.h>

#define Bn 4
#define An 3
#define Hn 168
#define Wn 256
#define Mn 32
#define HWn (Hn*Wn)
#define Nn (HWn*An)          // 129024
#define POS_CAP 8192
#define NPERIM 256
#define NPOSMAX 128
#define FG_THR 0.7f
#define BG_THR 0.3f
#define BETA (1.0f/9.0f)

#define NBLK 504             // blocks per image (APT=1: occupancy hides atomics)
#define NWAVES (NBLK*4)      // 2016 waves per image
#define TSEG_CAP 64          // per-wave deferred segment
#define NSEG_CAP 64          // per-wave certain-negative fallback segment
#define XSEG_CAP 256         // per-k2-block late-negative fallback segment
#define BIN_HOT 960          // bins >= BIN_HOT bucketed (top-64 bins ~2900 >> k_neg<=256)
#define NHOT 64
#define HB_CAP 256
#define CM_STRIDE 16         // 64B per CM word: atomicMax streams don't share lines

// ---- workspace layout (uint32 word offsets) ----
// BINBCE is GONE (R10 lesson: per-negative float atomics = write amplification +
// per-neg exp/log in the hot loop; selected negatives are only ~250/image and live
// in the hot buckets -> compute their BCE lazily in k3).
#define OFF_POSCNT 0            // Bn
#define OFF_COUNT  8            // 1
#define OFF_CLS    9            // 1 (float bits)
#define OFF_REG    10           // 1 (float bits)
#define OFF_DONEA  11           // 1 (cross-image ticket, k3 only: 4 blocks)
#define OFF_BINCNT 16           // Bn*1024 -> 4112
#define OFF_CM     4112         // Bn*32*CM_STRIDE = 2048 -> 6160
#define ZERO_WORDS 6160
#define OFF_WPCM   6160         // Bn*NWAVES*32 = 258048 -> 264208
#define OFF_TSEGC  264208       // Bn*NWAVES = 8064    -> 272272
#define OFF_NSEGC  272272       // Bn*NWAVES = 8064    -> 280336
#define OFF_XSEGC  280336       // Bn*NBLK = 2016      -> 282352
#define OFF_PLIST  282352       // Bn*POS_CAP*2 = 65536 -> 347888
#define OFF_HBUCK  347888       // Bn*NHOT*HB_CAP*2 = 131072 -> 478960
#define OFF_TSEG   478960       // Bn*NWAVES*TSEG_CAP*4 = 2064384 -> 2543344 (16B-aligned)
#define OFF_NSEG   2543344      // Bn*NWAVES*NSEG_CAP*2 = 1032192 -> 3575536
#define OFF_XSEG   3575536      // Bn*NBLK*XSEG_CAP*2 = 1032192 -> 4607728 (~18.4MB)

// ------------------- threefry2x32 (20 rounds) -------------------
__device__ __forceinline__ uint32_t rotl32(uint32_t v, int n) { return (v << n) | (v >> (32 - n)); }

__device__ __forceinline__ void tf2x32(uint32_t k0, uint32_t k1, uint32_t x0, uint32_t x1,
                                       uint32_t& o0, uint32_t& o1) {
    uint32_t k2 = k0 ^ k1 ^ 0x1BD11BDAu;
    x0 += k0; x1 += k1;
    x0 += x1; x1 = rotl32(x1, 13); x1 ^= x0;
    x0 += x1; x1 = rotl32(x1, 15); x1 ^= x0;
    x0 += x1; x1 = rotl32(x1, 26); x1 ^= x0;
    x0 += x1; x1 = rotl32(x1, 6);  x1 ^= x0;
    x0 += k1; x1 += k2 + 1u;
    x0 += x1; x1 = rotl32(x1, 17); x1 ^= x0;
    x0 += x1; x1 = rotl32(x1, 29); x1 ^= x0;
    x0 += x1; x1 = rotl32(x1, 16); x1 ^= x0;
    x0 += x1; x1 = rotl32(x1, 24); x1 ^= x0;
    x0 += k2; x1 += k0 + 2u;
    x0 += x1; x1 = rotl32(x1, 13); x1 ^= x0;
    x0 += x1; x1 = rotl32(x1, 15); x1 ^= x0;
    x0 += x1; x1 = rotl32(x1, 26); x1 ^= x0;
    x0 += x1; x1 = rotl32(x1, 6);  x1 ^= x0;
    x0 += k0; x1 += k1 + 3u;
    x0 += x1; x1 = rotl32(x1, 17); x1 ^= x0;
    x0 += x1; x1 = rotl32(x1, 29); x1 ^= x0;
    x0 += x1; x1 = rotl32(x1, 16); x1 ^= x0;
    x0 += x1; x1 = rotl32(x1, 24); x1 ^= x0;
    x0 += k1; x1 += k2 + 4u;
    x0 += x1; x1 = rotl32(x1, 13); x1 ^= x0;
    x0 += x1; x1 = rotl32(x1, 15); x1 ^= x0;
    x0 += x1; x1 = rotl32(x1, 26); x1 ^= x0;
    x0 += x1; x1 = rotl32(x1, 6);  x1 ^= x0;
    x0 += k2; x1 += k0 + 5u;
    o0 = x0; o1 = x1;
}

__device__ __forceinline__ uint32_t rng_m23(uint32_t k0, uint32_t k1, uint32_t i) {
    uint32_t o0, o1;
    tf2x32(k0, k1, 0u, i, o0, o1);
    return (o0 ^ o1) >> 9;
}

// ------------------- IoU (single definition) ------------
__device__ __forceinline__ float iou_one(float a0, float a1, float a2, float a3,
                                         float t0, float t1, float t2, float t3) {
    float xtl = fmaxf(a0, t0), ytl = fmaxf(a1, t1);
    float xrb = fminf(a2, t2), yrb = fminf(a3, t3);
    float iw = fmaxf(xrb - xtl + 1.0f, 0.0f);
    float ih = fmaxf(yrb - ytl + 1.0f, 0.0f);
    float inter = iw * ih;
    float area1 = (a2 - a0 + 1.0f) * (a3 - a1 + 1.0f);
    float area2 = (t2 - t0 + 1.0f) * (t3 - t1 + 1.0f);
    return inter * __builtin_amdgcn_rcpf(area1 + area2 - inter);
}

__device__ __forceinline__ float bce0(float l) {   // BCE(l, target=0)
    return fmaxf(l, 0.0f) + log1pf(expf(-fabsf(l)));
}

// ------------------- selection order (JAX top_k) -------------------
__device__ __forceinline__ bool sel_less(uint2 a, uint2 b) {
    return (a.x > b.x) || (a.x == b.x && a.y < b.y);
}

__device__ void bitonic_sort_shared(uint2* buf, int n) {   // n = pow2
    for (int k = 2; k <= n; k <<= 1) {
        for (int j = k >> 1; j > 0; j >>= 1) {
            for (int t = (int)threadIdx.x; t < n; t += (int)blockDim.x) {
                int ixj = t ^ j;
                if (ixj > t) {
                    uint2 x = buf[t], y = buf[ixj];
                    bool up = ((t & k) == 0);
                    bool sw = up ? sel_less(y, x) : sel_less(x, y);
                    if (sw) { buf[t] = y; buf[ixj] = x; }
                }
            }
            __syncthreads();
        }
    }
}

// =====================================================================================
// K0: zero control + bin counters + CM.
// =====================================================================================
__global__ void __launch_bounds__(256) k0_init(uint32_t* __restrict__ ws) {
    int i = blockIdx.x * 256 + (int)threadIdx.x;
    if (i < ZERO_WORDS) ws[i] = 0u;
}

// =====================================================================================
// K1: IoU + categorize. One anchor/thread. NO logits access, NO per-neg BCE atomic.
//  pos -> PLIST ticket (rare). defer -> per-wave TSEG (no atomics).
//  neg -> NSEG (ballot-compacted) + BINCNT atomic (count only); hot bins also bucket.
//  Global colmax: 32 fire-and-forget atomicMax/block into padded CM.
//  No fences/tickets (R8/R9: in-kernel device-scope release = ~180us; boundary = ~10us).
// =====================================================================================
__global__ void __launch_bounds__(256) k1_iou(const float* __restrict__ anchors,
                                              const float* __restrict__ targets,
                                              const float* __restrict__ sizes,
                                              uint32_t* __restrict__ ws) {
    const int b = blockIdx.y, j = blockIdx.x, tid = threadIdx.x;
    const int wid = tid >> 6, lane = tid & 63;
    __shared__ float part[4][Mn];

    uint32_t key0, key1;
    tf2x32(0u, 42u, 0u, (uint32_t)b, key0, key1);

    const int i = j * 256 + tid;
    float4 av = ((const float4*)anchors)[b * Nn + i];

    float rowmax = -1.0f; int ori = 0; uint32_t tie = 0u;
    float mycm = 0.0f;   // lane t (t<32) ends holding wave colmax of target t
    #pragma unroll 4
    for (int t = 0; t < Mn; ++t) {
        float4 tv = ((const float4*)targets)[b * Mn + t];
        float io = iou_one(av.x, av.y, av.z, av.w, tv.x, tv.y, tv.z, tv.w);
        if (io > rowmax) { rowmax = io; ori = t; }
        float m0 = io;
        #pragma unroll
        for (int o = 32; o > 0; o >>= 1) m0 = fmaxf(m0, __shfl_xor(m0, o, 64));
        if (lane == t) mycm = m0;
        tie |= (io == m0) ? (1u << t) : 0u;
    }

    const int wimg = j * 4 + wid;
    if (lane < Mn) {
        ws[OFF_WPCM + ((size_t)b * NWAVES + wimg) * 32 + lane] = __float_as_uint(mycm);
        part[wid][lane] = mycm;
    }
    __syncthreads();
    if (tid < Mn) {
        float v = fmaxf(fmaxf(part[0][tid], part[1][tid]),
                        fmaxf(part[2][tid], part[3][tid]));
        atomicMax(&ws[OFF_CM + (b * 32 + tid) * CM_STRIDE], __float_as_uint(v));
    }

    const float sh = sizes[b * 2 + 0], sw = sizes[b * 2 + 1];
    unsigned long long lt_mask = (lane == 63) ? 0x7FFFFFFFFFFFFFFFull
                                              : ((1ull << lane) - 1ull);
    bool inside = (av.x >= 0.0f) && (av.y >= 0.0f) &&
                  (av.z <= sw - 1.0f) && (av.w <= sh - 1.0f);
    bool fg = rowmax >= FG_THR;
    bool bg = rowmax < BG_THR;
    bool posn   = inside && fg;
    bool defern = inside && !fg && (tie != 0u);
    bool negn   = inside && bg && (tie == 0u);
    uint32_t m = rng_m23(key0, key1, (uint32_t)i);

    unsigned long long pmask = __ballot(posn);
    if (pmask) {
        int leader = __ffsll((long long)pmask) - 1;
        uint32_t bb = 0;
        if (lane == leader) bb = atomicAdd(&ws[OFF_POSCNT + b], (uint32_t)__popcll(pmask));
        bb = __shfl(bb, leader, 64);
        if (posn) {
            uint32_t p = bb + (uint32_t)__popcll(pmask & lt_mask);
            if (p < POS_CAP)
                ((uint2*)(ws + OFF_PLIST))[(size_t)b * POS_CAP + p] =
                    make_uint2(m, (uint32_t)i | ((uint32_t)ori << 17));
        }
    }
    unsigned long long dmask = __ballot(defern);
    if (defern) {
        uint32_t slot = (uint32_t)__popcll(dmask & lt_mask);
        ((uint4*)(ws + OFF_TSEG))[((size_t)b * NWAVES + wimg) * TSEG_CAP + slot] =
            make_uint4(tie, m,
                       (uint32_t)i | ((uint32_t)ori << 17) | (bg ? (1u << 22) : 0u), 0u);
    }
    unsigned long long nmask = __ballot(negn);
    if (negn) {
        uint32_t slot = (uint32_t)__popcll(nmask & lt_mask);
        ((uint2*)(ws + OFF_NSEG))[((size_t)b * NWAVES + wimg) * NSEG_CAP + slot] =
            make_uint2(m, (uint32_t)i);
        int bin = (int)(m >> 13);
        if (bin >= BIN_HOT) {
            uint32_t s2 = atomicAdd(&ws[OFF_BINCNT + (b << 10) + bin], 1u);   // returning (6%)
            if (s2 < HB_CAP)
                ((uint2*)(ws + OFF_HBUCK))[((size_t)b * NHOT + (bin - BIN_HOT)) * HB_CAP + s2] =
                    make_uint2(m, (uint32_t)i);
        } else {
            atomicAdd(&ws[OFF_BINCNT + (b << 10) + bin], 1u);                 // fire-and-forget
        }
    }
    if (lane == 0) {
        ws[OFF_TSEGC + b * NWAVES + wimg] = (uint32_t)__popcll(dmask);
        ws[OFF_NSEGC + b * NWAVES + wimg] = (uint32_t)__popcll(nmask);
    }
}

// =====================================================================================
// K2: lightweight distributed tie-resolve. Reads CM (128B, L2-hit) + own 4 waves'
// WPCM (512B) -> eqmasks -> resolves ~26 entries. Plain stores; kernel boundary
// provides visibility. No logits, no BCE.
// =====================================================================================
__global__ void __launch_bounds__(256) k2_resolve(uint32_t* __restrict__ ws) {
    const int b = blockIdx.y, j = blockIdx.x, tid = threadIdx.x;
    const int lane = tid & 63;
    __shared__ uint32_t cmb[Mn];
    __shared__ uint32_t eqs[4];
    __shared__ uint32_t cnts[4];
    __shared__ uint32_t sx_cnt;

    if (tid < 4) { eqs[tid] = 0u; cnts[tid] = ws[OFF_TSEGC + b * NWAVES + j * 4 + tid]; }
    if (tid == 0) sx_cnt = 0u;
    if (tid < Mn) cmb[tid] = ws[OFF_CM + (b * 32 + tid) * CM_STRIDE];
    __syncthreads();
    const int total = (int)(cnts[0] + cnts[1] + cnts[2] + cnts[3]);
    if (total > 0) {
        if (tid < 128) {
            int lw = tid >> 5, t2 = tid & 31;
            uint32_t wv = ws[OFF_WPCM + ((size_t)b * NWAVES + j * 4 + lw) * 32 + t2];
            if (wv == cmb[t2]) atomicOr(&eqs[lw], 1u << t2);
        }
        __syncthreads();

        const uint32_t c0 = cnts[0], c1 = cnts[1], c2 = cnts[2], c3 = cnts[3];
        unsigned long long lt_mask = (lane == 63) ? 0x7FFFFFFFFFFFFFFFull
                                                  : ((1ull << lane) - 1ull);
        for (int f = tid; f < total; f += 256) {
            int lw, o;
            if ((uint32_t)f < c0)                { lw = 0; o = f; }
            else if ((uint32_t)f < c0 + c1)      { lw = 1; o = f - (int)c0; }
            else if ((uint32_t)f < c0 + c1 + c2) { lw = 2; o = f - (int)(c0 + c1); }
            else                                 { lw = 3; o = f - (int)(c0 + c1 + c2); }
            uint4 e = ((const uint4*)(ws + OFF_TSEG))
                          [((size_t)b * NWAVES + j * 4 + lw) * TSEG_CAP + o];
            int i = (int)(e.z & 0x1FFFFu);
            bool restored = (e.x & eqs[lw]) != 0u;

            unsigned long long rmask = __ballot(restored);
            if (rmask) {
                int leader = __ffsll((long long)rmask) - 1;
                uint32_t bb = 0;
                if (lane == leader) bb = atomicAdd(&ws[OFF_POSCNT + b], (uint32_t)__popcll(rmask));
                bb = __shfl(bb, leader, 64);
                if (restored) {
                    uint32_t p = bb + (uint32_t)__popcll(rmask & lt_mask);
                    if (p < POS_CAP)
                        ((uint2*)(ws + OFF_PLIST))[(size_t)b * POS_CAP + p] =
                            make_uint2(e.y, e.z & 0x3FFFFFu);   // strip bg bit
                }
            }
            if (!restored && (e.z & (1u << 22))) {   // late negative
                uint32_t m = e.y;
                int bin = (int)(m >> 13);
                if (bin >= BIN_HOT) {
                    uint32_t s2 = atomicAdd(&ws[OFF_BINCNT + (b << 10) + bin], 1u);
                    if (s2 < HB_CAP)
                        ((uint2*)(ws + OFF_HBUCK))
                            [((size_t)b * NHOT + (bin - BIN_HOT)) * HB_CAP + s2] =
                                make_uint2(m, (uint32_t)i);
                } else {
                    atomicAdd(&ws[OFF_BINCNT + (b << 10) + bin], 1u);
                }
                uint32_t xs = atomicAdd(&sx_cnt, 1u);    // LDS
                if (xs < XSEG_CAP)
                    ((uint2*)(ws + OFF_XSEG))[((size_t)b * NBLK + j) * XSEG_CAP + xs] =
                        make_uint2(m, (uint32_t)i);
            }
        }
    }
    __syncthreads();
    if (tid == 0) ws[OFF_XSEGC + b * NBLK + j] = sx_cnt;
}

// =====================================================================================
// K3: per-image finalize, 1024 threads, 1 block/image. Lazy BCE: iterate the included
// hot buckets (~250 selected negatives) and load their logits here, instead of a
// per-negative float atomic in k1. Fallback to exact NSEG/XSEG scan if boundary is
// below BIN_HOT or an included bucket overflowed (probability ~0; correctness always).
// =====================================================================================
__global__ void __launch_bounds__(1024) k3_final(const float* __restrict__ anchors,
                                                 const float* __restrict__ targets,
                                                 const float* __restrict__ logits,
                                                 const float* __restrict__ bregs,
                                                 uint32_t* __restrict__ ws,
                                                 float* __restrict__ out) {
    const int b = blockIdx.x, tid = threadIdx.x;
    __shared__ uint32_t csum[1024];
    __shared__ uint2 buf[2048];
    __shared__ float fred[1024];
    __shared__ uint32_t hcnt[NHOT];
    __shared__ int s_bd, s_need, s_fb;
    __shared__ uint32_t s_fcnt;
    float cls = 0.0f, reg = 0.0f;

    // ---- suffix scan of bin counts (bin == tid) ----
    csum[tid] = ws[OFF_BINCNT + (b << 10) + tid];
    __syncthreads();
    for (int off = 1; off < 1024; off <<= 1) {
        uint32_t v = csum[tid];
        uint32_t add = (tid + off < 1024) ? csum[tid + off] : 0u;
        __syncthreads();
        csum[tid] = v + add;
        __syncthreads();
    }
    uint32_t pc = ws[OFF_POSCNT + b];            // final (incl. restored)
    int num_pos = (pc < (uint32_t)NPOSMAX) ? (int)pc : NPOSMAX;
    int k_neg = NPERIM - num_pos;
    uint32_t total = csum[0];
    if (tid == 0) {
        if ((int)total < k_neg) { s_bd = -1; s_need = 0; }
        s_fb = 0;
        s_fcnt = 0u;
    }
    {
        uint32_t inclv = csum[tid];
        uint32_t nxt = (tid < 1023) ? csum[tid + 1] : 0u;
        if ((int)total >= k_neg && (int)inclv >= k_neg && (int)nxt < k_neg) {
            s_bd = tid; s_need = k_neg - (int)nxt;
        }
    }
    if (tid == 0) {
        int sel_negs = ((int)total < k_neg) ? (int)total : k_neg;
        atomicAdd(&ws[OFF_COUNT], (uint32_t)(num_pos + sel_negs));
    }
    if (tid < NHOT) hcnt[tid] = ws[OFF_BINCNT + (b << 10) + BIN_HOT + tid];
    __syncthreads();
    const int bd = s_bd, need = s_need;

    // fallback decision: boundary below hot range, or an included/boundary hot bucket
    // overflowed its capacity
    if (tid < NHOT) {
        int bin = BIN_HOT + (int)tid;
        if (bin >= bd && hcnt[tid] > (uint32_t)HB_CAP) s_fb = 1;
    }
    if (tid == 0 && bd < BIN_HOT) s_fb = 1;
    __syncthreads();
    const int fb = s_fb;

    if (!fb) {
        // ---- included hot bins: lazy BCE over bucket entries (~k_neg - need loads) ----
        const uint2* hbk = (const uint2*)(ws + OFF_HBUCK) + (size_t)b * NHOT * HB_CAP;
        for (int idx = tid; idx < NHOT * HB_CAP; idx += 1024) {
            int hb = idx >> 8;                  // / HB_CAP
            int slot = idx & (HB_CAP - 1);
            int bin = BIN_HOT + hb;
            if (bin > bd && slot < (int)hcnt[hb]) {
                int i = (int)hbk[hb * HB_CAP + slot].y;
                int a = i % An, hw = i / An;
                cls += bce0(logits[(b * An + a) * HWn + hw]);
            }
        }
        // ---- boundary bin: sort bucket, take top-`need` ----
        if (need > 0) {
            int cnt = (int)hcnt[bd - BIN_HOT];
            if (cnt > HB_CAP) cnt = HB_CAP;     // guarded by fb check
            const uint2* bkt = hbk + (bd - BIN_HOT) * HB_CAP;
            for (int t = tid; t < cnt; t += 1024) buf[t] = bkt[t];
            int npad = 1; while (npad < cnt) npad <<= 1;
            for (int t = tid; t < npad; t += 1024) if (t >= cnt) buf[t] = make_uint2(0u, 0xFFFFFFFFu);
            __syncthreads();
            bitonic_sort_shared(buf, npad);
            int sel = (need < cnt) ? need : cnt;
            for (int t = tid; t < sel; t += 1024) {
                int i = (int)buf[t].y;
                int a = i % An, hw = i / An;
                cls += bce0(logits[(b * An + a) * HWn + hw]);
            }
        }
    } else {
        // ---- exact fallback: scan NSEG + XSEG; bin>bd -> direct BCE; bin==bd -> collect
        for (int w = tid >> 6; w < NWAVES; w += 16) {
            int cw = (int)ws[OFF_NSEGC + b * NWAVES + w];
            const uint2* ns = (const uint2*)(ws + OFF_NSEG) +
                              ((size_t)b * NWAVES + w) * NSEG_CAP;
            for (int idx = (tid & 63); idx < cw; idx += 64) {
                uint2 e = ns[idx];
                int bin = (int)(e.x >> 13);
                if (bin > bd) {
                    int i = (int)e.y;
                    int a = i % An, hw = i / An;
                    cls += bce0(logits[(b * An + a) * HWn + hw]);
                } else if (bin == bd) {
                    uint32_t q2 = atomicAdd(&s_fcnt, 1u);
                    if (q2 < 2048u) buf[q2] = e;
                }
            }
        }
        for (int j2 = tid >> 6; j2 < NBLK; j2 += 16) {
            int cx = (int)ws[OFF_XSEGC + b * NBLK + j2];
            if (cx > XSEG_CAP) cx = XSEG_CAP;
            const uint2* xs = (const uint2*)(ws + OFF_XSEG) +
                              ((size_t)b * NBLK + j2) * XSEG_CAP;
            for (int idx = (tid & 63); idx < cx; idx += 64) {
                uint2 e = xs[idx];
                int bin = (int)(e.x >> 13);
                if (bin > bd) {
                    int i = (int)e.y;
                    int a = i % An, hw = i / An;
                    cls += bce0(logits[(b * An + a) * HWn + hw]);
                } else if (bin == bd) {
                    uint32_t q2 = atomicAdd(&s_fcnt, 1u);
                    if (q2 < 2048u) buf[q2] = e;
                }
            }
        }
        __syncthreads();
        int cnt = (int)s_fcnt; if (cnt > 2048) cnt = 2048;
        if (need > 0 && cnt > 0) {
            int npad = 1; while (npad < cnt) npad <<= 1;
            for (int t = tid; t < npad; t += 1024) if (t >= cnt) buf[t] = make_uint2(0u, 0xFFFFFFFFu);
            __syncthreads();
            bitonic_sort_shared(buf, npad);
            int sel = (need < cnt) ? need : cnt;
            for (int t = tid; t < sel; t += 1024) {
                int i = (int)buf[t].y;
                int a = i % An, hw = i / An;
                cls += bce0(logits[(b * An + a) * HWn + hw]);
            }
        }
    }
    __syncthreads();

    // ---- positives ----
    {
        int pci = (pc < (uint32_t)POS_CAP) ? (int)pc : POS_CAP;
        const uint2* plist = (const uint2*)(ws + OFF_PLIST) + (size_t)b * POS_CAP;
        int psel = (pci < NPOSMAX) ? pci : NPOSMAX;
        bool use_buf = false;
        if (pci > NPOSMAX) {
            int n = (pci < 2048) ? pci : 2048;
            for (int t = tid; t < n; t += 1024) buf[t] = plist[t];
            int npad = 1; while (npad < n) npad <<= 1;
            for (int t = tid; t < npad; t += 1024) if (t >= n) buf[t] = make_uint2(0u, 0xFFFFFFFFu);
            __syncthreads();
            bitonic_sort_shared(buf, npad);
            use_buf = true;
            psel = (NPOSMAX < n) ? NPOSMAX : n;
        }
        for (int t = tid; t < psel; t += 1024) {
            uint32_t packed = use_buf ? buf[t].y : plist[t].y;
            int i = (int)(packed & 0x1FFFFu);
            int orit = (int)((packed >> 17) & 0x1Fu);
            int a = i % An, hw = i / An;
            float l = logits[(b * An + a) * HWn + hw];
            cls += fmaxf(l, 0.0f) - l + log1pf(expf(-fabsf(l)));   // BCE(l,1)
            float4 avx = ((const float4*)anchors)[b * Nn + i];
            float4 tv = ((const float4*)targets)[b * Mn + orit];
            float aws = avx.z - avx.x + 1.0f, ahs = avx.w - avx.y + 1.0f;
            float axc = avx.x + 0.5f * aws, ayc = avx.y + 0.5f * ahs;
            float tws = tv.z - tv.x + 1.0f, ths = tv.w - tv.y + 1.0f;
            float txc = tv.x + 0.5f * tws, tyc = tv.y + 0.5f * ths;
            float off0 = (txc - axc) / aws;
            float off1 = (tyc - ayc) / ahs;
            float off2 = logf(tws / aws);
            float off3 = logf(ths / ahs);
            float br0 = bregs[(b * 12 + a * 4 + 0) * HWn + hw];
            float br1 = bregs[(b * 12 + a * 4 + 1) * HWn + hw];
            float br2 = bregs[(b * 12 + a * 4 + 2) * HWn + hw];
            float br3 = bregs[(b * 12 + a * 4 + 3) * HWn + hw];
            float d;
            d = fabsf(br0 - off0); reg += (d < BETA) ? 0.5f * d * d / BETA : d - 0.5f * BETA;
            d = fabsf(br1 - off1); reg += (d < BETA) ? 0.5f * d * d / BETA : d - 0.5f * BETA;
            d = fabsf(br2 - off2); reg += (d < BETA) ? 0.5f * d * d / BETA : d - 0.5f * BETA;
            d = fabsf(br3 - off3); reg += (d < BETA) ? 0.5f * d * d / BETA : d - 0.5f * BETA;
        }
    }

    // ---- reductions + cross-image epilogue ----
    fred[tid] = cls;
    __syncthreads();
    for (int s = 512; s > 0; s >>= 1) {
        if (tid < s) fred[tid] += fred[tid + s];
        __syncthreads();
    }
    if (tid == 0 && fred[0] != 0.0f) atomicAdd((float*)&ws[OFF_CLS], fred[0]);
    __syncthreads();
    fred[tid] = reg;
    __syncthreads();
    for (int s = 512; s > 0; s >>= 1) {
        if (tid < s) fred[tid] += fred[tid + s];
        __syncthreads();
    }
    if (tid == 0) {
        if (fred[0] != 0.0f) atomicAdd((float*)&ws[OFF_REG], fred[0]);
        __threadfence();
        uint32_t old = atomicAdd(&ws[OFF_DONEA], 1u);
        if (old == Bn - 1) {
            float cls_tot = __uint_as_float(atomicAdd(&ws[OFF_CLS], 0u));
            float reg_tot = __uint_as_float(atomicAdd(&ws[OFF_REG], 0u));
            float cnt = (float)atomicAdd(&ws[OFF_COUNT], 0u);
            out[0] = cls_tot / cnt;
            out[1] = reg_tot / cnt;
        }
    }
}

extern "C" void kernel_launch(void* const* d_in, const int* in_sizes, int n_in,
                              void* d_out, int out_size, void* d_ws, size_t ws_size,
                              hipStream_t stream) {
    const float* anchors = (const float*)d_in[0];   // [B, N, 4]
    const float* logits  = (const float*)d_in[1];   // [B, A, H, W]
    const float* bregs   = (const float*)d_in[2];   // [B, 4A, H, W]
    const float* sizes   = (const float*)d_in[3];   // [B, 2]
    const float* targets = (const float*)d_in[4];   // [B, M, 4]
    float* out = (float*)d_out;
    uint32_t* ws = (uint32_t*)d_ws;

    k0_init<<<dim3((ZERO_WORDS + 255) / 256), dim3(256), 0, stream>>>(ws);
    k1_iou<<<dim3(NBLK, Bn), dim3(256), 0, stream>>>(anchors, targets, sizes, ws);
    k2_resolve<<<dim3(NBLK, Bn), dim3(256), 0, stream>>>(ws);
    k3_final<<<dim3(Bn), dim3(1024), 0, stream>>>(anchors, targets, logits, bregs, ws, out);
}